// Round 1
// baseline (43805.722 us; speedup 1.0000x reference)
//
#include <hip/hip_runtime.h>
#include <math.h>

#define DIMX 512
#define NHEADS 8
#define DHE 64
#define NB 266
#define FFD 2048
#define OUTD 32
#define BATCH 4
#define SEQ 8192
#define NTOK 32768
#define NLAYER 6
#define PAIRB 2
#define PSEQ (PAIRB * SEQ)   // 16384 tokens per batch-pair
#define CH 32                // chunks per (b,h) in ctx/o

#define DN_F 0.35355339059327373f
#define RATIO_F 0.06131393f

typedef unsigned short ushort_t;
typedef __attribute__((ext_vector_type(8))) short short8;
typedef __attribute__((ext_vector_type(4))) float floatx4;

__device__ __forceinline__ float tanh_fast(float x) {
    // 1 - 2/(e^2x+1); saturates correctly at +-inf
    float e = __expf(2.0f * x);
    return 1.0f - 2.0f / (e + 1.0f);
}

__device__ __forceinline__ float gelu_f(float x) {
    float x3 = x * x * x;
    return 0.5f * x * (1.0f + tanh_fast(0.7978845608028654f * (x + 0.044715f * x3)));
}

__device__ __forceinline__ ushort_t f2bf(float f) {
    unsigned int u = __float_as_uint(f);
    unsigned int r = (u + 0x7fffu + ((u >> 16) & 1u)) >> 16;
    return (ushort_t)r;
}

__device__ __forceinline__ unsigned int fkey(float f) {
    unsigned int u = __float_as_uint(f);
    return (u & 0x80000000u) ? ~u : (u | 0x80000000u);
}
__device__ __forceinline__ float funkey(unsigned int k) {
    unsigned int u = (k & 0x80000000u) ? (k & 0x7fffffffu) : ~k;
    return __uint_as_float(u);
}

// async global->LDS 16B per lane; LDS dest = wave-uniform base + lane*16
__device__ __forceinline__ void gl_lds16(const void* g, void* l) {
    __builtin_amdgcn_global_load_lds(
        (const __attribute__((address_space(1))) unsigned int*)g,
        (__attribute__((address_space(3))) unsigned int*)l, 16, 0, 0);
}

__global__ __launch_bounds__(256) void zero_kernel(float* __restrict__ p, int n) {
    int i = blockIdx.x * 256 + threadIdx.x;
    if (i < n) p[i] = 0.f;
}

// ---------------- LayerNorm -> bf16 out: one wave per 512-float row ----------------
__global__ __launch_bounds__(256) void ln_bf16_kernel(const float* __restrict__ x,
                                                      const float* __restrict__ g,
                                                      const float* __restrict__ b,
                                                      ushort_t* __restrict__ out) {
    int row = blockIdx.x * 4 + (threadIdx.x >> 6);
    int lane = threadIdx.x & 63;
    const float4* xr = (const float4*)(x + (size_t)row * DIMX);
    float4 v0 = xr[lane];
    float4 v1 = xr[lane + 64];
    float sum = v0.x + v0.y + v0.z + v0.w + v1.x + v1.y + v1.z + v1.w;
#pragma unroll
    for (int off = 32; off; off >>= 1) sum += __shfl_xor(sum, off);
    float mu = sum * (1.0f / 512.0f);
    float var = (v0.x - mu) * (v0.x - mu) + (v0.y - mu) * (v0.y - mu) +
                (v0.z - mu) * (v0.z - mu) + (v0.w - mu) * (v0.w - mu) +
                (v1.x - mu) * (v1.x - mu) + (v1.y - mu) * (v1.y - mu) +
                (v1.z - mu) * (v1.z - mu) + (v1.w - mu) * (v1.w - mu);
#pragma unroll
    for (int off = 32; off; off >>= 1) var += __shfl_xor(var, off);
    float rstd = rsqrtf(var * (1.0f / 512.0f) + 1e-5f);
    const float4* g4 = (const float4*)g;
    const float4* b4 = (const float4*)b;
    ushort_t* orow = out + (size_t)row * DIMX;
    float4 gg = g4[lane], bb = b4[lane];
    ushort4 o;
    o.x = f2bf((v0.x - mu) * rstd * gg.x + bb.x);
    o.y = f2bf((v0.y - mu) * rstd * gg.y + bb.y);
    o.z = f2bf((v0.z - mu) * rstd * gg.z + bb.z);
    o.w = f2bf((v0.w - mu) * rstd * gg.w + bb.w);
    *(ushort4*)(orow + lane * 4) = o;
    gg = g4[lane + 64]; bb = b4[lane + 64];
    o.x = f2bf((v1.x - mu) * rstd * gg.x + bb.x);
    o.y = f2bf((v1.y - mu) * rstd * gg.y + bb.y);
    o.z = f2bf((v1.z - mu) * rstd * gg.z + bb.z);
    o.w = f2bf((v1.w - mu) * rstd * gg.w + bb.w);
    *(ushort4*)(orow + 256 + lane * 4) = o;
}

// ---------------- weight transpose-convert: W[K,N] fp32 -> Wt[N,K] bf16 ----------------
__global__ __launch_bounds__(256) void wconv_kernel(const float* __restrict__ W,
                                                    ushort_t* __restrict__ Wt,
                                                    int K, int N) {
    __shared__ float tile[32][33];
    int bx = blockIdx.x * 32;  // n
    int by = blockIdx.y * 32;  // k
    int tx = threadIdx.x & 31, ty = threadIdx.x >> 5;
#pragma unroll
    for (int r = 0; r < 4; r++)
        tile[ty + r * 8][tx] = W[(size_t)(by + ty + r * 8) * N + bx + tx];
    __syncthreads();
#pragma unroll
    for (int r = 0; r < 4; r++)
        Wt[(size_t)(bx + ty + r * 8) * K + by + tx] = f2bf(tile[tx][ty + r * 8]);
}

// ---------------- bf16 MFMA GEMM: 128x128 tile, 16x16x32, m97 structure ----------------
// A[M,K] bf16 row-major; Bt[N,K] bf16 row-major (i.e. B transposed).
// EPI 0: C = A@B (fp32). EPI 1: C += A@B + bias (fp32). EPI 2: Cb = bf16(gelu(A@B + bias)).
template <int EPI>
__global__ __launch_bounds__(256) void gemm_mfma(const ushort_t* __restrict__ A,
                                                 const ushort_t* __restrict__ Bt,
                                                 const float* __restrict__ bias,
                                                 float* __restrict__ C,
                                                 ushort_t* __restrict__ Cb,
                                                 int M, int N, int K) {
    __shared__ ushort_t As[128 * 32];
    __shared__ ushort_t Bs[128 * 32];
    int t = threadIdx.x;
    int wave = t >> 6, lane = t & 63;
    int wm = wave >> 1, wn = wave & 1;
    int m0 = blockIdx.x * 128, n0 = blockIdx.y * 128;
    int q = lane >> 4, ml = lane & 15;

    floatx4 acc[4][4];
#pragma unroll
    for (int i = 0; i < 4; i++)
#pragma unroll
        for (int j = 0; j < 4; j++) acc[i][j] = (floatx4)(0.f);

    int srow = (lane >> 2);
    int scol = (lane & 3) * 8;
    const ushort_t* Ag = A + (size_t)(m0 + wave * 32 + srow) * K + scol;
    const ushort_t* Bg = Bt + (size_t)(n0 + wave * 32 + srow) * K + scol;
    ushort_t* AsW = &As[(wave * 32) * 32];
    ushort_t* BsW = &Bs[(wave * 32) * 32];

    for (int k0 = 0; k0 < K; k0 += 32) {
        gl_lds16(Ag + k0, AsW);
        gl_lds16(Ag + k0 + (size_t)16 * K, AsW + 16 * 32);
        gl_lds16(Bg + k0, BsW);
        gl_lds16(Bg + k0 + (size_t)16 * K, BsW + 16 * 32);
        __syncthreads();
        short8 a[4], b[4];
#pragma unroll
        for (int i = 0; i < 4; i++)
            a[i] = *(const short8*)&As[(wm * 64 + i * 16 + ml) * 32 + q * 8];
#pragma unroll
        for (int j = 0; j < 4; j++)
            b[j] = *(const short8*)&Bs[(wn * 64 + j * 16 + ml) * 32 + q * 8];
#pragma unroll
        for (int i = 0; i < 4; i++)
#pragma unroll
            for (int j = 0; j < 4; j++)
                acc[i][j] = __builtin_amdgcn_mfma_f32_16x16x32_bf16(a[i], b[j], acc[i][j], 0, 0, 0);
        __syncthreads();
    }

    // C/D layout: col = lane&15, row = (lane>>4)*4 + reg
#pragma unroll
    for (int i = 0; i < 4; i++) {
#pragma unroll
        for (int r = 0; r < 4; r++) {
            size_t row = (size_t)m0 + wm * 64 + i * 16 + q * 4 + r;
#pragma unroll
            for (int j = 0; j < 4; j++) {
                int col = n0 + wn * 64 + j * 16 + ml;
                float v = acc[i][j][r];
                if (EPI == 0) {
                    C[row * N + col] = v;
                } else if (EPI == 1) {
                    C[row * N + col] += v + bias[col];
                } else {
                    Cb[row * N + col] = f2bf(gelu_f(v + bias[col]));
                }
            }
        }
    }
}

// ---------------- fp32 VALU GEMM (kept for final fc, N=32) ----------------
template <int DOACC, int DOGELU>
__global__ __launch_bounds__(256) void gemm_kernel(const float* __restrict__ A,
                                                   const float* __restrict__ B,
                                                   const float* __restrict__ bias,
                                                   float* __restrict__ C,
                                                   int M, int N, int K) {
    __shared__ float As[16][132];
    __shared__ float Bs[16][132];
    int t = threadIdx.x;
    int tx = t & 15, ty = t >> 4;
    int m0 = blockIdx.x * 128;
    int n0 = blockIdx.y * 128;
    float c[8][8];
#pragma unroll
    for (int i = 0; i < 8; i++)
#pragma unroll
        for (int j = 0; j < 8; j++) c[i][j] = 0.f;
    int am = t >> 1;
    int ak = (t & 1) * 8;
    const float* Aptr = A + (size_t)(m0 + am) * K + ak;
    int bn = (t & 15) * 8;
    int bk = t >> 4;
    bool bvalid = (n0 + bn) < N;
    const float* Bptr = B + (size_t)bk * N + n0 + bn;
    for (int k0 = 0; k0 < K; k0 += 16) {
        float4 a0 = *(const float4*)(Aptr + k0);
        float4 a1 = *(const float4*)(Aptr + k0 + 4);
        As[ak + 0][am] = a0.x; As[ak + 1][am] = a0.y;
        As[ak + 2][am] = a0.z; As[ak + 3][am] = a0.w;
        As[ak + 4][am] = a1.x; As[ak + 5][am] = a1.y;
        As[ak + 6][am] = a1.z; As[ak + 7][am] = a1.w;
        float4 b0 = make_float4(0.f, 0.f, 0.f, 0.f);
        float4 b1v = make_float4(0.f, 0.f, 0.f, 0.f);
        if (bvalid) {
            const float* bp = Bptr + (size_t)k0 * N;
            b0 = *(const float4*)bp;
            b1v = *(const float4*)(bp + 4);
        }
        *(float4*)&Bs[bk][bn] = b0;
        *(float4*)&Bs[bk][bn + 4] = b1v;
        __syncthreads();
#pragma unroll
        for (int kk = 0; kk < 16; kk++) {
            float4 av0 = *(const float4*)&As[kk][ty * 4];
            float4 av1 = *(const float4*)&As[kk][64 + ty * 4];
            float4 bv0 = *(const float4*)&Bs[kk][tx * 4];
            float4 bv1 = *(const float4*)&Bs[kk][64 + tx * 4];
            float a_[8] = {av0.x, av0.y, av0.z, av0.w, av1.x, av1.y, av1.z, av1.w};
            float b_[8] = {bv0.x, bv0.y, bv0.z, bv0.w, bv1.x, bv1.y, bv1.z, bv1.w};
#pragma unroll
            for (int i = 0; i < 8; i++)
#pragma unroll
                for (int j = 0; j < 8; j++) c[i][j] += a_[i] * b_[j];
        }
        __syncthreads();
    }
#pragma unroll
    for (int ih = 0; ih < 2; ih++)
#pragma unroll
        for (int il = 0; il < 4; il++) {
            size_t row = (size_t)m0 + ih * 64 + ty * 4 + il;
#pragma unroll
            for (int jh = 0; jh < 2; jh++) {
                int colbase = n0 + jh * 64 + tx * 4;
                if (colbase < N) {
                    float* cp = C + row * N + colbase;
#pragma unroll
                    for (int jl = 0; jl < 4; jl++) {
                        float v = c[ih * 4 + il][jh * 4 + jl];
                        if (bias) v += bias[colbase + jl];
                        if (DOGELU) v = gelu_f(v);
                        if (DOACC) v += cp[jl];
                        cp[jl] = v;
                    }
                }
            }
        }
}

// ---------------- global max over key features (pair-batched) ----------------
__global__ __launch_bounds__(320) void kmax_kernel(const float* __restrict__ Kf,
                                                   const float* __restrict__ proj,
                                                   unsigned int* __restrict__ kmaxkey,
                                                   int rows_per_block) {
    int tid = threadIdx.x;
    float4 pr[16];
    if (tid < NB) {
#pragma unroll
        for (int j = 0; j < 16; j++) pr[j] = ((const float4*)proj)[tid * 16 + j];
    }
    float lmax = -3.0e38f;
    size_t r0 = (size_t)blockIdx.x * rows_per_block;
    for (int r = 0; r < rows_per_block; r++) {
        const float4* kr = (const float4*)(Kf + (r0 + r) * DHE);
        if (tid < NB) {
            float acc = 0.f;
#pragma unroll
            for (int j = 0; j < 16; j++) {
                float4 kv = kr[j];
                acc += kv.x * pr[j].x + kv.y * pr[j].y + kv.z * pr[j].z + kv.w * pr[j].w;
            }
            lmax = fmaxf(lmax, acc);
        }
    }
    lmax *= DN_F;
#pragma unroll
    for (int off = 32; off; off >>= 1) lmax = fmaxf(lmax, __shfl_xor(lmax, off));
    __shared__ float wmax[5];
    if ((tid & 63) == 0) wmax[tid >> 6] = lmax;
    __syncthreads();
    if (tid == 0) {
        float bm = wmax[0];
        for (int w = 1; w < 5; w++) bm = fmaxf(bm, wmax[w]);
        atomicMax(kmaxkey, fkey(bm));
    }
}

// ------------- fused kp + ctx/ksum accumulation, batched over pair -------------
// grid = PAIRB * NHEADS * CH blocks of 320 threads
__global__ __launch_bounds__(320, 3) void ctx_kernel(const float* __restrict__ Kf,
                                                     const float* __restrict__ Vf,
                                                     const float* __restrict__ proj,
                                                     const unsigned int* __restrict__ kmaxkey,
                                                     float* __restrict__ CTX,
                                                     float* __restrict__ KSUM) {
    __shared__ float kps[NB];
    __shared__ float vrow[DHE];
    int tid = threadIdx.x;
    int bh = blockIdx.x / CH;          // b*NHEADS + h
    int ch = blockIdx.x - bh * CH;
    int b = bh >> 3;
    int h = bh & 7;
    const float* Kb = Kf + (size_t)b * SEQ * DIMX;
    const float* Vb = Vf + (size_t)b * SEQ * DIMX;
    float4 pr[16];
    if (tid < NB) {
#pragma unroll
        for (int j = 0; j < 16; j++) pr[j] = ((const float4*)proj)[tid * 16 + j];
    }
    float mx = funkey(*kmaxkey);
    float cacc[54];
#pragma unroll
    for (int k = 0; k < 54; k++) cacc[k] = 0.f;
    float ksum_r = 0.f;
    int w = tid >> 6, d = tid & 63;
    const int ntk = SEQ / CH;
    int nbase = ch * ntk;
    for (int n = 0; n < ntk; n++) {
        size_t tg = (size_t)(nbase + n);
        const float4* kr = (const float4*)(Kb + tg * DIMX + h * DHE);
        if (tid < NB) {
            float acc = 0.f, ss = 0.f;
#pragma unroll
            for (int j = 0; j < 16; j++) {
                float4 kv = kr[j];
                acc += kv.x * pr[j].x + kv.y * pr[j].y + kv.z * pr[j].z + kv.w * pr[j].w;
                ss += kv.x * kv.x + kv.y * kv.y + kv.z * kv.z + kv.w * kv.w;
            }
            float kp = RATIO_F * (__expf(acc * DN_F - ss * 0.0625f - mx) + 1e-4f);
            kps[tid] = kp;
            ksum_r += kp;
        }
        if (tid < 16)
            ((float4*)vrow)[tid] = ((const float4*)(Vb + tg * DIMX + h * DHE))[tid];
        __syncthreads();
        float vv = vrow[d];
#pragma unroll
        for (int k = 0; k < 54; k++) {
            int m = w + 5 * k;
            if (m < NB) cacc[k] += kps[m] * vv;
        }
        __syncthreads();
    }
    float* ctxp = CTX + (size_t)bh * (NB * DHE);
#pragma unroll
    for (int k = 0; k < 54; k++) {
        int m = w + 5 * k;
        if (m < NB) atomicAdd(&ctxp[m * DHE + d], cacc[k]);
    }
    if (tid < NB) atomicAdd(&KSUM[(size_t)bh * NB + tid], ksum_r);
}

// ------------- fused qp + o = d_inv * (qp @ ctx); bf16 output; pair-batched -------------
__global__ __launch_bounds__(320, 3) void o_kernel(const float* __restrict__ Qf,
                                                   const float* __restrict__ proj,
                                                   const float* __restrict__ CTX,
                                                   const float* __restrict__ KSUM,
                                                   ushort_t* __restrict__ Of) {
    __shared__ float qps[NB];
    __shared__ float redm[5];
    __shared__ float reds[5];
    __shared__ float opart[5][DHE];
    int tid = threadIdx.x;
    int bh = blockIdx.x / CH;
    int ch = blockIdx.x - bh * CH;
    int b = bh >> 3;
    int h = bh & 7;
    const float* Qb = Qf + (size_t)b * SEQ * DIMX;
    ushort_t* Ob = Of + (size_t)b * SEQ * DIMX;
    float4 pr[16];
    if (tid < NB) {
#pragma unroll
        for (int j = 0; j < 16; j++) pr[j] = ((const float4*)proj)[tid * 16 + j];
    }
    int w = tid >> 6, d = tid & 63;
    float creg[54];
#pragma unroll
    for (int k = 0; k < 54; k++) {
        int m = w + 5 * k;
        creg[k] = (m < NB) ? CTX[(size_t)bh * (NB * DHE) + m * DHE + d] : 0.f;
    }
    float ksum_r = (tid < NB) ? KSUM[(size_t)bh * NB + tid] : 0.f;
    const int ntk = SEQ / CH;
    int nbase = ch * ntk;
    for (int n = 0; n < ntk; n++) {
        size_t tg = (size_t)(nbase + n);
        const float4* qr = (const float4*)(Qb + tg * DIMX + h * DHE);
        float xp = -3.0e38f, ss = 0.f;
        if (tid < NB) {
            float acc = 0.f;
#pragma unroll
            for (int j = 0; j < 16; j++) {
                float4 qv = qr[j];
                acc += qv.x * pr[j].x + qv.y * pr[j].y + qv.z * pr[j].z + qv.w * pr[j].w;
                ss += qv.x * qv.x + qv.y * qv.y + qv.z * qv.z + qv.w * qv.w;
            }
            xp = acc * DN_F;
        }
        float lm = xp;
#pragma unroll
        for (int off = 32; off; off >>= 1) lm = fmaxf(lm, __shfl_xor(lm, off));
        if ((tid & 63) == 0) redm[w] = lm;
        __syncthreads();
        float rmax = fmaxf(fmaxf(fmaxf(redm[0], redm[1]), fmaxf(redm[2], redm[3])), redm[4]);
        float dp = 0.f;
        if (tid < NB) {
            float qp = RATIO_F * (__expf(xp - ss * 0.0625f - rmax) + 1e-4f);
            qps[tid] = qp;
            dp = qp * ksum_r;
        }
#pragma unroll
        for (int off = 32; off; off >>= 1) dp += __shfl_xor(dp, off);
        if ((tid & 63) == 0) reds[w] = dp;
        __syncthreads();
        float denom = reds[0] + reds[1] + reds[2] + reds[3] + reds[4];
        float dinv = 1.0f / denom;
        float op = 0.f;
#pragma unroll
        for (int k = 0; k < 54; k++) {
            int m = w + 5 * k;
            if (m < NB) op += qps[m] * creg[k];
        }
        opart[w][d] = op;
        __syncthreads();
        if (tid < DHE) {
            float o = opart[0][tid] + opart[1][tid] + opart[2][tid] + opart[3][tid] +
                      opart[4][tid];
            Ob[tg * DIMX + h * DHE + tid] = f2bf(o * dinv);
        }
        __syncthreads();
    }
}

extern "C" void kernel_launch(void* const* d_in, const int* in_sizes, int n_in,
                              void* d_out, int out_size, void* d_ws, size_t ws_size,
                              hipStream_t stream) {
    (void)in_sizes; (void)n_in; (void)out_size; (void)ws_size;
    const float* src  = (const float*)d_in[0];
    const float* proj = (const float*)d_in[1];
    const float* ln1g = (const float*)d_in[2];
    const float* ln1b = (const float*)d_in[3];
    const float* Wq   = (const float*)d_in[4];
    const float* Wk   = (const float*)d_in[5];
    const float* Wv   = (const float*)d_in[6];
    const float* Wo   = (const float*)d_in[7];
    const float* bo   = (const float*)d_in[8];
    const float* ln2g = (const float*)d_in[9];
    const float* ln2b = (const float*)d_in[10];
    const float* W1   = (const float*)d_in[11];
    const float* b1   = (const float*)d_in[12];
    const float* W2   = (const float*)d_in[13];
    const float* b2   = (const float*)d_in[14];
    const float* fcw  = (const float*)d_in[15];
    const float* fcb  = (const float*)d_in[16];
    float* out = (float*)d_out;

    // Workspace layout (~151 MiB; 162 known-safe)
    const size_t TD = (size_t)NTOK * DIMX;   // all tokens
    const size_t SD = (size_t)SEQ * DIMX;    // one batch
    const size_t PD = (size_t)PSEQ * DIMX;   // one pair (2 batches)
    float* X     = (float*)d_ws;             // 64 MiB residual fp32
    float* C     = X + TD;                   // 32 MiB pair fp32 (K, then Q)
    float* D     = C + PD;                   // 32 MiB pair fp32 (V; then Ob bf16 alias)
    float* CTXb  = D + PD;                   // 2*8*266*64 fp32
    float* KSUMb = CTXb + (size_t)PAIRB * NHEADS * NB * DHE;  // 2*8*266
    unsigned int* KMAX = (unsigned int*)(KSUMb + (size_t)PAIRB * NHEADS * NB);
    ushort_t* Hs  = (ushort_t*)(KMAX + 4);   // 16 MiB pair LN out bf16
    ushort_t* Wtb = Hs + PD;                 // 6 MiB per-layer weights bf16 (transposed)
    ushort_t* Wqt = Wtb;
    ushort_t* Wkt = Wqt + DIMX * DIMX;
    ushort_t* Wvt = Wkt + DIMX * DIMX;
    ushort_t* Wot = Wvt + DIMX * DIMX;
    ushort_t* W1t = Wot + DIMX * DIMX;        // [FFD, DIMX]
    ushort_t* W2t = W1t + (size_t)DIMX * FFD; // [DIMX, FFD]
    ushort_t* Hid = (ushort_t*)C;             // 64 MiB alias over C+D (FF hidden)
    ushort_t* Ob  = (ushort_t*)D;             // 16 MiB alias over D (attn out bf16)
    const int nzero = PAIRB * NHEADS * NB * DHE + PAIRB * NHEADS * NB;

    hipMemcpyAsync(X, src, sizeof(float) * TD, hipMemcpyDeviceToDevice, stream);

    dim3 gP(PSEQ / 128, DIMX / 128);   // (128,4)  M=16384,N=512
    dim3 gF1(PSEQ / 128, FFD / 128);   // (128,16) M=16384,N=2048
    const int lnGrid = PSEQ / 4;       // 4096
    const int ctxGrid = PAIRB * NHEADS * CH;  // 512
    for (int L = 0; L < NLAYER; L++) {
        const float* pj = proj + (size_t)L * NB * DHE;
        // --- per-layer weight transpose-convert to bf16 ---
        wconv_kernel<<<dim3(16, 16), 256, 0, stream>>>(Wq + (size_t)L * DIMX * DIMX, Wqt, DIMX, DIMX);
        wconv_kernel<<<dim3(16, 16), 256, 0, stream>>>(Wk + (size_t)L * DIMX * DIMX, Wkt, DIMX, DIMX);
        wconv_kernel<<<dim3(16, 16), 256, 0, stream>>>(Wv + (size_t)L * DIMX * DIMX, Wvt, DIMX, DIMX);
        wconv_kernel<<<dim3(16, 16), 256, 0, stream>>>(Wo + (size_t)L * DIMX * DIMX, Wot, DIMX, DIMX);
        wconv_kernel<<<dim3(64, 16), 256, 0, stream>>>(W1 + (size_t)L * DIMX * FFD, W1t, DIMX, FFD);
        wconv_kernel<<<dim3(16, 64), 256, 0, stream>>>(W2 + (size_t)L * FFD * DIMX, W2t, FFD, DIMX);
        zero_kernel<<<1, 256, 0, stream>>>((float*)KMAX, 1);
        // --- pass 1: K per pair -> global key max (over all 4 batches) ---
        for (int p = 0; p < 2; p++) {
            const float* Xp = X + (size_t)p * PD;
            ln_bf16_kernel<<<lnGrid, 256, 0, stream>>>(Xp, ln1g + L * DIMX, ln1b + L * DIMX, Hs);
            gemm_mfma<0><<<gP, 256, 0, stream>>>(Hs, Wkt, nullptr, C, nullptr, PSEQ, DIMX, DIMX);
            kmax_kernel<<<2048, 320, 0, stream>>>(C, pj, KMAX, (PSEQ * NHEADS) / 2048);
        }
        // --- pass 2: attention + FF per pair (p=1 first: Hs/C still hold pair-1 LN1/K) ---
        for (int pp = 0; pp < 2; pp++) {
            int p = 1 - pp;
            float* Xp = X + (size_t)p * PD;
            if (p == 0) {
                ln_bf16_kernel<<<lnGrid, 256, 0, stream>>>(Xp, ln1g + L * DIMX, ln1b + L * DIMX, Hs);
                gemm_mfma<0><<<gP, 256, 0, stream>>>(Hs, Wkt, nullptr, C, nullptr, PSEQ, DIMX, DIMX);
            }
            gemm_mfma<0><<<gP, 256, 0, stream>>>(Hs, Wvt, nullptr, D, nullptr, PSEQ, DIMX, DIMX);
            zero_kernel<<<(nzero + 255) / 256, 256, 0, stream>>>(CTXb, nzero);
            ctx_kernel<<<ctxGrid, 320, 0, stream>>>(C, D, pj, KMAX, CTXb, KSUMb);
            gemm_mfma<0><<<gP, 256, 0, stream>>>(Hs, Wqt, nullptr, C, nullptr, PSEQ, DIMX, DIMX);
            o_kernel<<<ctxGrid, 320, 0, stream>>>(C, pj, CTXb, KSUMb, Ob);
            gemm_mfma<1><<<gP, 256, 0, stream>>>(Ob, Wot, bo + L * DIMX, Xp, nullptr, PSEQ, DIMX, DIMX);
            // --- FF ---
            ln_bf16_kernel<<<lnGrid, 256, 0, stream>>>(Xp, ln2g + L * DIMX, ln2b + L * DIMX, Hs);
            gemm_mfma<2><<<gF1, 256, 0, stream>>>(Hs, W1t, b1 + L * FFD, nullptr, Hid, PSEQ, FFD, DIMX);
            gemm_mfma<1><<<gP, 256, 0, stream>>>(Hid, W2t, b2 + L * DIMX, Xp, nullptr, PSEQ, DIMX, FFD);
        }
    }
    gemm_kernel<0, 0><<<dim3(NTOK / 128, 1), 256, 0, stream>>>(X, fcw, fcb, out, NTOK, OUTD, DIMX);
}

// Round 2
// 6740.072 us; speedup vs baseline: 6.4993x; 6.4993x over previous
//
#include <hip/hip_runtime.h>
#include <math.h>

#define DIMX 512
#define NHEADS 8
#define DHE 64
#define NB 266
#define MP 288          // NB padded to 18 MFMA col-tiles
#define MT 18           // MP/16
#define CTILES 9        // 72 ctx tiles / 8 waves
#define KPT_LD 136      // kpT row stride (128+8) to break banks
#define CTXT_LD 296     // ctxt row stride (288+8)
#define FFD 2048
#define OUTD 32
#define SEQ 8192
#define NTOK 32768
#define NLAYER 6
#define PSEQ 16384      // tokens per batch-pair

#define DN_F 0.35355339059327373f
#define RATIO_F 0.06131393f
#define EPS_F 1e-4f

typedef unsigned short ushort_t;
typedef __attribute__((ext_vector_type(8))) short short8;
typedef __attribute__((ext_vector_type(4))) float floatx4;

__device__ __forceinline__ float tanh_fast(float x) {
    float e = __expf(2.0f * x);
    return 1.0f - 2.0f / (e + 1.0f);
}

__device__ __forceinline__ float gelu_f(float x) {
    float x3 = x * x * x;
    return 0.5f * x * (1.0f + tanh_fast(0.7978845608028654f * (x + 0.044715f * x3)));
}

__device__ __forceinline__ ushort_t f2bf(float f) {
    unsigned int u = __float_as_uint(f);
    unsigned int r = (u + 0x7fffu + ((u >> 16) & 1u)) >> 16;
    return (ushort_t)r;
}

__device__ __forceinline__ float bf2f(ushort_t u) {
    return __uint_as_float(((unsigned int)u) << 16);
}

__device__ __forceinline__ unsigned int fkey(float f) {
    unsigned int u = __float_as_uint(f);
    return (u & 0x80000000u) ? ~u : (u | 0x80000000u);
}
__device__ __forceinline__ float funkey(unsigned int k) {
    unsigned int u = (k & 0x80000000u) ? (k & 0x7fffffffu) : ~k;
    return __uint_as_float(u);
}

// async global->LDS 16B per lane; LDS dest = wave-uniform base + lane*16
__device__ __forceinline__ void gl_lds16(const void* g, void* l) {
    __builtin_amdgcn_global_load_lds(
        (const __attribute__((address_space(1))) unsigned int*)g,
        (__attribute__((address_space(3))) unsigned int*)l, 16, 0, 0);
}

__global__ __launch_bounds__(256) void zero_kernel(float* __restrict__ p, int n) {
    int i = blockIdx.x * 256 + threadIdx.x;
    if (i < n) p[i] = 0.f;
}

// ---------------- LayerNorm -> bf16 out: one wave per 512-float row ----------------
__global__ __launch_bounds__(256) void ln_bf16_kernel(const float* __restrict__ x,
                                                      const float* __restrict__ g,
                                                      const float* __restrict__ b,
                                                      ushort_t* __restrict__ out) {
    int row = blockIdx.x * 4 + (threadIdx.x >> 6);
    int lane = threadIdx.x & 63;
    const float4* xr = (const float4*)(x + (size_t)row * DIMX);
    float4 v0 = xr[lane];
    float4 v1 = xr[lane + 64];
    float sum = v0.x + v0.y + v0.z + v0.w + v1.x + v1.y + v1.z + v1.w;
#pragma unroll
    for (int off = 32; off; off >>= 1) sum += __shfl_xor(sum, off);
    float mu = sum * (1.0f / 512.0f);
    float var = (v0.x - mu) * (v0.x - mu) + (v0.y - mu) * (v0.y - mu) +
                (v0.z - mu) * (v0.z - mu) + (v0.w - mu) * (v0.w - mu) +
                (v1.x - mu) * (v1.x - mu) + (v1.y - mu) * (v1.y - mu) +
                (v1.z - mu) * (v1.z - mu) + (v1.w - mu) * (v1.w - mu);
#pragma unroll
    for (int off = 32; off; off >>= 1) var += __shfl_xor(var, off);
    float rstd = rsqrtf(var * (1.0f / 512.0f) + 1e-5f);
    const float4* g4 = (const float4*)g;
    const float4* b4 = (const float4*)b;
    ushort_t* orow = out + (size_t)row * DIMX;
    float4 gg = g4[lane], bb = b4[lane];
    ushort4 o;
    o.x = f2bf((v0.x - mu) * rstd * gg.x + bb.x);
    o.y = f2bf((v0.y - mu) * rstd * gg.y + bb.y);
    o.z = f2bf((v0.z - mu) * rstd * gg.z + bb.z);
    o.w = f2bf((v0.w - mu) * rstd * gg.w + bb.w);
    *(ushort4*)(orow + lane * 4) = o;
    gg = g4[lane + 64]; bb = b4[lane + 64];
    o.x = f2bf((v1.x - mu) * rstd * gg.x + bb.x);
    o.y = f2bf((v1.y - mu) * rstd * gg.y + bb.y);
    o.z = f2bf((v1.z - mu) * rstd * gg.z + bb.z);
    o.w = f2bf((v1.w - mu) * rstd * gg.w + bb.w);
    *(ushort4*)(orow + 256 + lane * 4) = o;
}

// ---------------- weight transpose-convert: W[K,N] fp32 -> Wt[N,K] bf16 ----------------
__global__ __launch_bounds__(256) void wconv_kernel(const float* __restrict__ W,
                                                    ushort_t* __restrict__ Wt,
                                                    int K, int N) {
    __shared__ float tile[32][33];
    int bx = blockIdx.x * 32;  // n
    int by = blockIdx.y * 32;  // k
    int tx = threadIdx.x & 31, ty = threadIdx.x >> 5;
#pragma unroll
    for (int r = 0; r < 4; r++)
        tile[ty + r * 8][tx] = W[(size_t)(by + ty + r * 8) * N + bx + tx];
    __syncthreads();
#pragma unroll
    for (int r = 0; r < 4; r++)
        Wt[(size_t)(bx + ty + r * 8) * K + by + tx] = f2bf(tile[tx][ty + r * 8]);
}

// ---------------- proj fp32 [266][64] -> bf16 [288][64] (pad rows zero) ----------------
__global__ __launch_bounds__(256) void projconv_kernel(const float* __restrict__ proj,
                                                       ushort_t* __restrict__ Pbf) {
    int i = blockIdx.x * 256 + threadIdx.x;
    if (i < MP * DHE) {
        int m = i >> 6;
        Pbf[i] = (m < NB) ? f2bf(proj[i]) : (ushort_t)0;
    }
}

// ---------------- per-token per-head sum of squares from bf16 matrix ----------------
// M [PSEQ][512] bf16 -> SS [8][PSEQ] fp32
__global__ __launch_bounds__(256) void ss_kernel(const ushort_t* __restrict__ M,
                                                 float* __restrict__ SS) {
    int row = blockIdx.x * 4 + (threadIdx.x >> 6);
    int lane = threadIdx.x & 63;
    const ushort4* mr = (const ushort4*)(M + (size_t)row * DIMX);
    ushort4 u0 = mr[lane * 2], u1 = mr[lane * 2 + 1];
    float a, s = 0.f;
    a = bf2f(u0.x); s += a * a;  a = bf2f(u0.y); s += a * a;
    a = bf2f(u0.z); s += a * a;  a = bf2f(u0.w); s += a * a;
    a = bf2f(u1.x); s += a * a;  a = bf2f(u1.y); s += a * a;
    a = bf2f(u1.z); s += a * a;  a = bf2f(u1.w); s += a * a;
    s += __shfl_xor(s, 1); s += __shfl_xor(s, 2); s += __shfl_xor(s, 4);
    if ((lane & 7) == 0) SS[(lane >> 3) * PSEQ + row] = s;
}

// ---------------- bf16 MFMA GEMM: 128x128 tile, 16x16x32, m97 structure ----------------
// A[M,K] bf16 row-major; Bt[N,K] bf16 row-major.
// EPI 0: C = A@B fp32. EPI 1: C += A@B + bias. EPI 2: Cb = bf16(gelu(A@B+bias)).
// EPI 3: Cb = bf16(A@B). EPI 4: transposed per-head bf16: Vt[(b*8+h)*64+d][8192].
template <int EPI>
__global__ __launch_bounds__(256) void gemm_mfma(const ushort_t* __restrict__ A,
                                                 const ushort_t* __restrict__ Bt,
                                                 const float* __restrict__ bias,
                                                 float* __restrict__ C,
                                                 ushort_t* __restrict__ Cb,
                                                 int M, int N, int K) {
    __shared__ ushort_t As[128 * 32];
    __shared__ ushort_t Bs[128 * 32];
    int t = threadIdx.x;
    int wave = t >> 6, lane = t & 63;
    int wm = wave >> 1, wn = wave & 1;
    int m0 = blockIdx.x * 128, n0 = blockIdx.y * 128;
    int q = lane >> 4, ml = lane & 15;

    floatx4 acc[4][4];
#pragma unroll
    for (int i = 0; i < 4; i++)
#pragma unroll
        for (int j = 0; j < 4; j++) acc[i][j] = (floatx4)(0.f);

    int srow = (lane >> 2);
    int scol = (lane & 3) * 8;
    const ushort_t* Ag = A + (size_t)(m0 + wave * 32 + srow) * K + scol;
    const ushort_t* Bg = Bt + (size_t)(n0 + wave * 32 + srow) * K + scol;
    ushort_t* AsW = &As[(wave * 32) * 32];
    ushort_t* BsW = &Bs[(wave * 32) * 32];

    for (int k0 = 0; k0 < K; k0 += 32) {
        gl_lds16(Ag + k0, AsW);
        gl_lds16(Ag + k0 + (size_t)16 * K, AsW + 16 * 32);
        gl_lds16(Bg + k0, BsW);
        gl_lds16(Bg + k0 + (size_t)16 * K, BsW + 16 * 32);
        __syncthreads();
        short8 a[4], b[4];
#pragma unroll
        for (int i = 0; i < 4; i++)
            a[i] = *(const short8*)&As[(wm * 64 + i * 16 + ml) * 32 + q * 8];
#pragma unroll
        for (int j = 0; j < 4; j++)
            b[j] = *(const short8*)&Bs[(wn * 64 + j * 16 + ml) * 32 + q * 8];
#pragma unroll
        for (int i = 0; i < 4; i++)
#pragma unroll
            for (int j = 0; j < 4; j++)
                acc[i][j] = __builtin_amdgcn_mfma_f32_16x16x32_bf16(a[i], b[j], acc[i][j], 0, 0, 0);
        __syncthreads();
    }

    if (EPI == 4) {
#pragma unroll
        for (int i = 0; i < 4; i++) {
            size_t r0 = (size_t)m0 + wm * 64 + i * 16 + q * 4;
            int bb = (int)(r0 >> 13);
            int nl = (int)(r0 & (SEQ - 1));
#pragma unroll
            for (int j = 0; j < 4; j++) {
                int col = n0 + wn * 64 + j * 16 + ml;
                int hh = col >> 6, dd = col & 63;
                ushort4 pk;
                pk.x = f2bf(acc[i][j][0]); pk.y = f2bf(acc[i][j][1]);
                pk.z = f2bf(acc[i][j][2]); pk.w = f2bf(acc[i][j][3]);
                *(ushort4*)&Cb[(((size_t)bb * 8 + hh) * DHE + dd) * SEQ + nl] = pk;
            }
        }
    } else {
#pragma unroll
        for (int i = 0; i < 4; i++) {
#pragma unroll
            for (int r = 0; r < 4; r++) {
                size_t row = (size_t)m0 + wm * 64 + i * 16 + q * 4 + r;
#pragma unroll
                for (int j = 0; j < 4; j++) {
                    int col = n0 + wn * 64 + j * 16 + ml;
                    float v = acc[i][j][r];
                    if (EPI == 0) {
                        C[row * N + col] = v;
                    } else if (EPI == 1) {
                        C[row * N + col] += v + bias[col];
                    } else if (EPI == 2) {
                        Cb[row * N + col] = f2bf(gelu_f(v + bias[col]));
                    } else {
                        Cb[row * N + col] = f2bf(v);
                    }
                }
            }
        }
    }
}

// ---------------- fp32 VALU GEMM (final fc, N=32) ----------------
template <int DOACC, int DOGELU>
__global__ __launch_bounds__(256) void gemm_kernel(const float* __restrict__ A,
                                                   const float* __restrict__ B,
                                                   const float* __restrict__ bias,
                                                   float* __restrict__ C,
                                                   int M, int N, int K) {
    __shared__ float As[16][132];
    __shared__ float Bs[16][132];
    int t = threadIdx.x;
    int tx = t & 15, ty = t >> 4;
    int m0 = blockIdx.x * 128;
    int n0 = blockIdx.y * 128;
    float c[8][8];
#pragma unroll
    for (int i = 0; i < 8; i++)
#pragma unroll
        for (int j = 0; j < 8; j++) c[i][j] = 0.f;
    int am = t >> 1;
    int ak = (t & 1) * 8;
    const float* Aptr = A + (size_t)(m0 + am) * K + ak;
    int bn = (t & 15) * 8;
    int bk = t >> 4;
    bool bvalid = (n0 + bn) < N;
    const float* Bptr = B + (size_t)bk * N + n0 + bn;
    for (int k0 = 0; k0 < K; k0 += 16) {
        float4 a0 = *(const float4*)(Aptr + k0);
        float4 a1 = *(const float4*)(Aptr + k0 + 4);
        As[ak + 0][am] = a0.x; As[ak + 1][am] = a0.y;
        As[ak + 2][am] = a0.z; As[ak + 3][am] = a0.w;
        As[ak + 4][am] = a1.x; As[ak + 5][am] = a1.y;
        As[ak + 6][am] = a1.z; As[ak + 7][am] = a1.w;
        float4 b0 = make_float4(0.f, 0.f, 0.f, 0.f);
        float4 b1v = make_float4(0.f, 0.f, 0.f, 0.f);
        if (bvalid) {
            const float* bp = Bptr + (size_t)k0 * N;
            b0 = *(const float4*)bp;
            b1v = *(const float4*)(bp + 4);
        }
        *(float4*)&Bs[bk][bn] = b0;
        *(float4*)&Bs[bk][bn + 4] = b1v;
        __syncthreads();
#pragma unroll
        for (int kk = 0; kk < 16; kk++) {
            float4 av0 = *(const float4*)&As[kk][ty * 4];
            float4 av1 = *(const float4*)&As[kk][64 + ty * 4];
            float4 bv0 = *(const float4*)&Bs[kk][tx * 4];
            float4 bv1 = *(const float4*)&Bs[kk][64 + tx * 4];
            float a_[8] = {av0.x, av0.y, av0.z, av0.w, av1.x, av1.y, av1.z, av1.w};
            float b_[8] = {bv0.x, bv0.y, bv0.z, bv0.w, bv1.x, bv1.y, bv1.z, bv1.w};
#pragma unroll
            for (int i = 0; i < 8; i++)
#pragma unroll
                for (int j = 0; j < 8; j++) c[i][j] += a_[i] * b_[j];
        }
        __syncthreads();
    }
#pragma unroll
    for (int ih = 0; ih < 2; ih++)
#pragma unroll
        for (int il = 0; il < 4; il++) {
            size_t row = (size_t)m0 + ih * 64 + ty * 4 + il;
#pragma unroll
            for (int jh = 0; jh < 2; jh++) {
                int colbase = n0 + jh * 64 + tx * 4;
                if (colbase < N) {
                    float* cp = C + row * N + colbase;
#pragma unroll
                    for (int jl = 0; jl < 4; jl++) {
                        float v = c[ih * 4 + il][jh * 4 + jl];
                        if (bias) v += bias[colbase + jl];
                        if (DOGELU) v = gelu_f(v);
                        if (DOACC) v += cp[jl];
                        cp[jl] = v;
                    }
                }
            }
        }
}

// ---------------- global key-feature max via MFMA: grid (128 tiles x 8 heads) ----------------
__global__ __launch_bounds__(512) void kmax_kernel(const ushort_t* __restrict__ Kbf,
                                                   const ushort_t* __restrict__ Pbf,
                                                   unsigned int* __restrict__ kmaxkey) {
    int tid = threadIdx.x;
    int w = tid >> 6, lane = tid & 63;
    int q = lane >> 4, ml = lane & 15;
    int h = blockIdx.x >> 7, tile = blockIdx.x & 127;
    int arow = tile * 128 + w * 16 + ml;
    short8 af0 = *(const short8*)&Kbf[(size_t)arow * DIMX + h * DHE + q * 8];
    short8 af1 = *(const short8*)&Kbf[(size_t)arow * DIMX + h * DHE + 32 + q * 8];
    float lm = -3.0e38f;
#pragma unroll
    for (int c = 0; c < 17; c++) {
        floatx4 xp = (floatx4)(0.f);
        short8 b0 = *(const short8*)&Pbf[(c * 16 + ml) * DHE + q * 8];
        short8 b1 = *(const short8*)&Pbf[(c * 16 + ml) * DHE + 32 + q * 8];
        xp = __builtin_amdgcn_mfma_f32_16x16x32_bf16(af0, b0, xp, 0, 0, 0);
        xp = __builtin_amdgcn_mfma_f32_16x16x32_bf16(af1, b1, xp, 0, 0, 0);
        if (c * 16 + ml < NB)
            lm = fmaxf(lm, fmaxf(fmaxf(xp[0], xp[1]), fmaxf(xp[2], xp[3])));
    }
    lm *= DN_F;
#pragma unroll
    for (int off = 32; off; off >>= 1) lm = fmaxf(lm, __shfl_xor(lm, off));
    if (lane == 0) atomicMax(kmaxkey, fkey(lm));
}

// ---------------- fused kp + CTX partial via MFMA ----------------
// grid 256 = 16 bh x 16 strips of 512 tokens; 8 waves.
// Kbf [PSEQ][512] bf16; Vt [16bh][64][8192] bf16; SS [8][PSEQ] f32.
// CTXP [16bh][16 strips][288][64] f32 partials; KSUM [16bh][288] atomic f32.
__global__ __launch_bounds__(512) void kctx_kernel(const ushort_t* __restrict__ Kbf,
                                                   const ushort_t* __restrict__ Pbf,
                                                   const float* __restrict__ SS,
                                                   const unsigned int* __restrict__ kmaxkey,
                                                   const ushort_t* __restrict__ Vt,
                                                   float* __restrict__ CTXP,
                                                   float* __restrict__ KSUM) {
    __shared__ ushort_t kpT[MP * KPT_LD];  // [m][token] bf16, 78336 B
    int tid = threadIdx.x;
    int w = tid >> 6, lane = tid & 63;
    int q = lane >> 4, ml = lane & 15;
    int bh = blockIdx.x >> 4, s = blockIdx.x & 15;
    int b = bh >> 3, h = bh & 7;
    float mx = funkey(*kmaxkey);
    floatx4 ctx[CTILES];
    float ksacc[MT];
#pragma unroll
    for (int i = 0; i < CTILES; i++) ctx[i] = (floatx4)(0.f);
#pragma unroll
    for (int c = 0; c < MT; c++) ksacc[c] = 0.f;

    for (int sub = 0; sub < 4; sub++) {
        int tb = b * SEQ + s * 512 + sub * 128;  // pair-token base of sub-tile
        int arow = tb + w * 16 + ml;
        short8 af0 = *(const short8*)&Kbf[(size_t)arow * DIMX + h * DHE + q * 8];
        short8 af1 = *(const short8*)&Kbf[(size_t)arow * DIMX + h * DHE + 32 + q * 8];
        float ssr[4];
#pragma unroll
        for (int r = 0; r < 4; r++) ssr[r] = SS[h * PSEQ + tb + w * 16 + q * 4 + r];
#pragma unroll
        for (int c = 0; c < MT; c++) {
            floatx4 xp = (floatx4)(0.f);
            short8 b0 = *(const short8*)&Pbf[(c * 16 + ml) * DHE + q * 8];
            short8 b1 = *(const short8*)&Pbf[(c * 16 + ml) * DHE + 32 + q * 8];
            xp = __builtin_amdgcn_mfma_f32_16x16x32_bf16(af0, b0, xp, 0, 0, 0);
            xp = __builtin_amdgcn_mfma_f32_16x16x32_bf16(af1, b1, xp, 0, 0, 0);
            int m = c * 16 + ml;
            bool val = m < NB;
            float kpv[4];
#pragma unroll
            for (int r = 0; r < 4; r++)
                kpv[r] = val ? RATIO_F * (__expf(xp[r] * DN_F - ssr[r] * 0.0625f - mx) + EPS_F)
                             : 0.f;
            ushort4 pk;
            pk.x = f2bf(kpv[0]); pk.y = f2bf(kpv[1]);
            pk.z = f2bf(kpv[2]); pk.w = f2bf(kpv[3]);
            *(ushort4*)&kpT[m * KPT_LD + w * 16 + q * 4] = pk;
            ksacc[c] += kpv[0] + kpv[1] + kpv[2] + kpv[3];
        }
        __syncthreads();
#pragma unroll
        for (int sk = 0; sk < 4; sk++) {
#pragma unroll
            for (int i = 0; i < CTILES; i++) {
                int tt = w * CTILES + i;
                int mt = tt >> 2, dt = tt & 3;
                short8 a = *(const short8*)&kpT[(mt * 16 + ml) * KPT_LD + sk * 32 + q * 8];
                short8 bv = *(const short8*)&Vt[((size_t)bh * DHE + dt * 16 + ml) * SEQ +
                                                s * 512 + sub * 128 + sk * 32 + q * 8];
                ctx[i] = __builtin_amdgcn_mfma_f32_16x16x32_bf16(a, bv, ctx[i], 0, 0, 0);
            }
        }
        __syncthreads();
    }
    float* cp = CTXP + ((size_t)bh * 16 + s) * (MP * DHE);
#pragma unroll
    for (int i = 0; i < CTILES; i++) {
        int tt = w * CTILES + i;
        int mt = tt >> 2, dt = tt & 3;
#pragma unroll
        for (int r = 0; r < 4; r++)
            cp[(mt * 16 + q * 4 + r) * DHE + dt * 16 + ml] = ctx[i][r];
    }
#pragma unroll
    for (int c = 0; c < MT; c++) {
        float s4 = ksacc[c];
        s4 += __shfl_xor(s4, 16);
        s4 += __shfl_xor(s4, 32);
        int m = c * 16 + ml;
        if (q == 0 && m < NB) atomicAdd(&KSUM[bh * MP + m], s4);
    }
}

// ---------------- reduce CTX partials over 16 strips ----------------
__global__ __launch_bounds__(256) void ctx_reduce_kernel(const float* __restrict__ CTXP,
                                                         float* __restrict__ CTX) {
    int i = blockIdx.x * 256 + threadIdx.x;  // 16*288*64
    if (i < 16 * MP * DHE) {
        int bh = i / (MP * DHE);
        int e = i - bh * (MP * DHE);
        float s = 0.f;
#pragma unroll
        for (int st = 0; st < 16; st++)
            s += CTXP[((size_t)bh * 16 + st) * (MP * DHE) + e];
        CTX[i] = s;
    }
}

// ---------------- fused qp + rowmax + denom + O = dinv*(qp@CTX) via MFMA ----------------
// grid 1024 = 16 bh x 64 tiles of 128 tokens; 8 waves.
__global__ __launch_bounds__(512) void qo_kernel(const ushort_t* __restrict__ Qbf,
                                                 const ushort_t* __restrict__ Pbf,
                                                 const float* __restrict__ SS,
                                                 const float* __restrict__ CTX,
                                                 const float* __restrict__ KSUM,
                                                 ushort_t* __restrict__ Ob) {
    __shared__ ushort_t ctxt[DHE * CTXT_LD];   // CTX^T bf16 [d][m], 37888 B
    __shared__ ushort_t qpA[8][2][16][40];     // per-wave double-buffered qp chunk
    __shared__ float ksl[MP];
    int tid = threadIdx.x;
    int w = tid >> 6, lane = tid & 63;
    int q = lane >> 4, ml = lane & 15;
    int bh = blockIdx.x >> 6, tile = blockIdx.x & 63;
    int b = bh >> 3, h = bh & 7;
    for (int e = tid; e < MP * DHE; e += 512) {
        int m = e >> 6, d = e & 63;
        ctxt[d * CTXT_LD + m] = f2bf(CTX[(size_t)bh * (MP * DHE) + e]);
    }
    for (int e = tid; e < MP; e += 512) ksl[e] = KSUM[bh * MP + e];
    __syncthreads();
    int nl = tile * 128 + w * 16;
    int arow = b * SEQ + nl + ml;
    short8 af0 = *(const short8*)&Qbf[(size_t)arow * DIMX + h * DHE + q * 8];
    short8 af1 = *(const short8*)&Qbf[(size_t)arow * DIMX + h * DHE + 32 + q * 8];
    floatx4 xp[MT];
#pragma unroll
    for (int c = 0; c < MT; c++) {
        xp[c] = (floatx4)(0.f);
        short8 b0 = *(const short8*)&Pbf[(c * 16 + ml) * DHE + q * 8];
        short8 b1 = *(const short8*)&Pbf[(c * 16 + ml) * DHE + 32 + q * 8];
        xp[c] = __builtin_amdgcn_mfma_f32_16x16x32_bf16(af0, b0, xp[c], 0, 0, 0);
        xp[c] = __builtin_amdgcn_mfma_f32_16x16x32_bf16(af1, b1, xp[c], 0, 0, 0);
    }
    float ssr[4], rm[4], dp[4], dinv[4];
#pragma unroll
    for (int r = 0; r < 4; r++) {
        ssr[r] = SS[h * PSEQ + b * SEQ + nl + q * 4 + r];
        rm[r] = -3.0e38f;
        dp[r] = 0.f;
    }
#pragma unroll
    for (int c = 0; c < MT; c++) {
        int m = c * 16 + ml;
        bool val = m < NB;
#pragma unroll
        for (int r = 0; r < 4; r++) {
            float tv = xp[c][r] * DN_F;
            xp[c][r] = tv;
            if (val) rm[r] = fmaxf(rm[r], tv);
        }
    }
#pragma unroll
    for (int r = 0; r < 4; r++) {
        rm[r] = fmaxf(rm[r], __shfl_xor(rm[r], 1));
        rm[r] = fmaxf(rm[r], __shfl_xor(rm[r], 2));
        rm[r] = fmaxf(rm[r], __shfl_xor(rm[r], 4));
        rm[r] = fmaxf(rm[r], __shfl_xor(rm[r], 8));
    }
#pragma unroll
    for (int c = 0; c < MT; c++) {
        int m = c * 16 + ml;
        bool val = m < NB;
        float km = ksl[m];
#pragma unroll
        for (int r = 0; r < 4; r++) {
            float v = val ? RATIO_F * (__expf(xp[c][r] - ssr[r] * 0.0625f - rm[r]) + EPS_F) : 0.f;
            xp[c][r] = v;
            dp[r] += v * km;
        }
    }
#pragma unroll
    for (int r = 0; r < 4; r++) {
        dp[r] += __shfl_xor(dp[r], 1);
        dp[r] += __shfl_xor(dp[r], 2);
        dp[r] += __shfl_xor(dp[r], 4);
        dp[r] += __shfl_xor(dp[r], 8);
        dinv[r] = 1.0f / dp[r];
    }
    floatx4 oacc[4];
#pragma unroll
    for (int dt = 0; dt < 4; dt++) oacc[dt] = (floatx4)(0.f);
#pragma unroll
    for (int ks = 0; ks < 9; ks++) {
        int buf = ks & 1;
#pragma unroll
        for (int cc = 0; cc < 2; cc++) {
            int c = 2 * ks + cc;
#pragma unroll
            for (int r = 0; r < 4; r++)
                qpA[w][buf][q * 4 + r][cc * 16 + ml] = f2bf(xp[c][r]);
        }
        __syncthreads();
        short8 a = *(const short8*)&qpA[w][buf][ml][q * 8];
#pragma unroll
        for (int dt = 0; dt < 4; dt++) {
            short8 bv = *(const short8*)&ctxt[(dt * 16 + ml) * CTXT_LD + ks * 32 + q * 8];
            oacc[dt] = __builtin_amdgcn_mfma_f32_16x16x32_bf16(a, bv, oacc[dt], 0, 0, 0);
        }
    }
#pragma unroll
    for (int dt = 0; dt < 4; dt++)
#pragma unroll
        for (int r = 0; r < 4; r++)
            Ob[(size_t)(b * SEQ + nl + q * 4 + r) * DIMX + h * DHE + dt * 16 + ml] =
                f2bf(oacc[dt][r] * dinv[r]);
}

extern "C" void kernel_launch(void* const* d_in, const int* in_sizes, int n_in,
                              void* d_out, int out_size, void* d_ws, size_t ws_size,
                              hipStream_t stream) {
    (void)in_sizes; (void)n_in; (void)out_size; (void)ws_size;
    const float* src  = (const float*)d_in[0];
    const float* proj = (const float*)d_in[1];
    const float* ln1g = (const float*)d_in[2];
    const float* ln1b = (const float*)d_in[3];
    const float* Wq   = (const float*)d_in[4];
    const float* Wk   = (const float*)d_in[5];
    const float* Wv   = (const float*)d_in[6];
    const float* Wo   = (const float*)d_in[7];
    const float* bo   = (const float*)d_in[8];
    const float* ln2g = (const float*)d_in[9];
    const float* ln2b = (const float*)d_in[10];
    const float* W1   = (const float*)d_in[11];
    const float* b1   = (const float*)d_in[12];
    const float* W2   = (const float*)d_in[13];
    const float* b2   = (const float*)d_in[14];
    const float* fcw  = (const float*)d_in[15];
    const float* fcb  = (const float*)d_in[16];
    float* out = (float*)d_out;

    // ---- workspace layout (~153.7 MiB) ----
    const size_t TD   = (size_t)NTOK * DIMX;   // 16.78M floats
    const size_t PD   = (size_t)PSEQ * DIMX;   // 8.39M elems
    float*    X    = (float*)d_ws;                      // 64 MiB residual fp32
    ushort_t* Hs   = (ushort_t*)(X + TD);               // 16 MiB LN out bf16 (pair)
    ushort_t* KQbf = Hs + PD;                           // 16 MiB K bf16, then Q bf16
    ushort_t* Vt   = KQbf + PD;                         // 16 MiB V^T per-head bf16
    ushort_t* Obuf = Vt + PD;                           // 16 MiB attn out bf16
    float*    CTXP = (float*)(Obuf + PD);               // 18 MiB ctx partials
    float*    CTX  = CTXP + (size_t)16 * 16 * MP * DHE; // 1.125 MiB
    float*    KSUM = CTX + (size_t)16 * MP * DHE;       // 16x288
    unsigned int* KMAX = (unsigned int*)(KSUM + 16 * MP);
    float*    SS   = (float*)(KMAX + 4);                // [8][PSEQ]
    ushort_t* Pbf  = (ushort_t*)(SS + (size_t)NHEADS * PSEQ);  // [288][64] bf16
    ushort_t* Wtb  = Pbf + MP * DHE;                    // 6 MiB weights bf16
    ushort_t* Wqt = Wtb;
    ushort_t* Wkt = Wqt + DIMX * DIMX;
    ushort_t* Wvt = Wkt + DIMX * DIMX;
    ushort_t* Wot = Wvt + DIMX * DIMX;
    ushort_t* W1t = Wot + DIMX * DIMX;         // [FFD, DIMX]
    ushort_t* W2t = W1t + (size_t)DIMX * FFD;  // [DIMX, FFD]
    ushort_t* Hid = KQbf;  // FF hidden 64 MiB: aliases KQbf+Vt+Obuf+CTXP (all dead in FF)

    hipMemcpyAsync(X, src, sizeof(float) * TD, hipMemcpyDeviceToDevice, stream);

    dim3 gP(PSEQ / 128, DIMX / 128);   // (128,4)
    dim3 gF1(PSEQ / 128, FFD / 128);   // (128,16)
    const int lnGrid = PSEQ / 4;       // 4096
    for (int L = 0; L < NLAYER; L++) {
        const float* pj = proj + (size_t)L * NB * DHE;
        wconv_kernel<<<dim3(16, 16), 256, 0, stream>>>(Wq + (size_t)L * DIMX * DIMX, Wqt, DIMX, DIMX);
        wconv_kernel<<<dim3(16, 16), 256, 0, stream>>>(Wk + (size_t)L * DIMX * DIMX, Wkt, DIMX, DIMX);
        wconv_kernel<<<dim3(16, 16), 256, 0, stream>>>(Wv + (size_t)L * DIMX * DIMX, Wvt, DIMX, DIMX);
        wconv_kernel<<<dim3(16, 16), 256, 0, stream>>>(Wo + (size_t)L * DIMX * DIMX, Wot, DIMX, DIMX);
        wconv_kernel<<<dim3(64, 16), 256, 0, stream>>>(W1 + (size_t)L * DIMX * FFD, W1t, DIMX, FFD);
        wconv_kernel<<<dim3(16, 64), 256, 0, stream>>>(W2 + (size_t)L * FFD * DIMX, W2t, FFD, DIMX);
        projconv_kernel<<<(MP * DHE + 255) / 256, 256, 0, stream>>>(pj, Pbf);
        zero_kernel<<<1, 256, 0, stream>>>((float*)KMAX, 1);
        // --- phase A: global key-feature max over both pairs ---
        for (int p = 0; p < 2; p++) {
            const float* Xp = X + (size_t)p * PD;
            ln_bf16_kernel<<<lnGrid, 256, 0, stream>>>(Xp, ln1g + L * DIMX, ln1b + L * DIMX, Hs);
            gemm_mfma<3><<<gP, 256, 0, stream>>>(Hs, Wkt, nullptr, nullptr, KQbf, PSEQ, DIMX, DIMX);
            kmax_kernel<<<1024, 512, 0, stream>>>(KQbf, Pbf, KMAX);
        }
        // --- phase B: attention + FF per pair (p=1 first: Hs/KQbf still hold pair-1) ---
        for (int pp = 0; pp < 2; pp++) {
            int p = 1 - pp;
            float* Xp = X + (size_t)p * PD;
            if (p == 0) {
                ln_bf16_kernel<<<lnGrid, 256, 0, stream>>>(Xp, ln1g + L * DIMX, ln1b + L * DIMX, Hs);
                gemm_mfma<3><<<gP, 256, 0, stream>>>(Hs, Wkt, nullptr, nullptr, KQbf, PSEQ, DIMX, DIMX);
            }
            gemm_mfma<4><<<gP, 256, 0, stream>>>(Hs, Wvt, nullptr, nullptr, Vt, PSEQ, DIMX, DIMX);
            ss_kernel<<<lnGrid, 256, 0, stream>>>(KQbf, SS);
            zero_kernel<<<(16 * MP + 255) / 256, 256, 0, stream>>>(KSUM, 16 * MP);
            kctx_kernel<<<256, 512, 0, stream>>>(KQbf, Pbf, SS, KMAX, Vt, CTXP, KSUM);
            ctx_reduce_kernel<<<(16 * MP * DHE + 255) / 256, 256, 0, stream>>>(CTXP, CTX);
            gemm_mfma<3><<<gP, 256, 0, stream>>>(Hs, Wqt, nullptr, nullptr, KQbf, PSEQ, DIMX, DIMX);
            ss_kernel<<<lnGrid, 256, 0, stream>>>(KQbf, SS);
            qo_kernel<<<1024, 512, 0, stream>>>(KQbf, Pbf, SS, CTX, KSUM, Obuf);
            gemm_mfma<1><<<gP, 256, 0, stream>>>(Obuf, Wot, bo + L * DIMX, Xp, nullptr, PSEQ, DIMX, DIMX);
            // --- FF ---
            ln_bf16_kernel<<<lnGrid, 256, 0, stream>>>(Xp, ln2g + L * DIMX, ln2b + L * DIMX, Hs);
            gemm_mfma<2><<<gF1, 256, 0, stream>>>(Hs, W1t, b1 + L * FFD, nullptr, Hid, PSEQ, FFD, DIMX);
            gemm_mfma<1><<<gP, 256, 0, stream>>>(Hid, W2t, b2 + L * DIMX, Xp, nullptr, PSEQ, DIMX, FFD);
        }
    }
    gemm_kernel<0, 0><<<dim3(NTOK / 128, 1), 256, 0, stream>>>(X, fcw, fcb, out, NTOK, OUTD, DIMX);
}

// Round 3
// 6609.721 us; speedup vs baseline: 6.6275x; 1.0197x over previous
//
#include <hip/hip_runtime.h>
#include <math.h>

#define DIMX 512
#define NHEADS 8
#define DHE 64
#define NB 266
#define MP 288          // NB padded to 18 MFMA col-tiles
#define MT 18           // MP/16
#define KPT_LD 136      // kpT row stride (128+8) to break banks
#define CTXT_LD 296     // ctxt row stride (288+8)
#define NSTRIP 32       // strips per (b,h) in kctx
#define FFD 2048
#define OUTD 32
#define SEQ 8192
#define NTOK 32768
#define NLAYER 6
#define PSEQ 16384      // tokens per batch-pair

#define DN_F 0.35355339059327373f
#define RATIO_F 0.06131393f
#define EPS_F 1e-4f

typedef unsigned short ushort_t;
typedef __attribute__((ext_vector_type(8))) short short8;
typedef __attribute__((ext_vector_type(4))) float floatx4;

__device__ __forceinline__ float tanh_fast(float x) {
    float e = __expf(2.0f * x);
    return 1.0f - 2.0f / (e + 1.0f);
}

__device__ __forceinline__ float gelu_f(float x) {
    float x3 = x * x * x;
    return 0.5f * x * (1.0f + tanh_fast(0.7978845608028654f * (x + 0.044715f * x3)));
}

__device__ __forceinline__ ushort_t f2bf(float f) {
    unsigned int u = __float_as_uint(f);
    unsigned int r = (u + 0x7fffu + ((u >> 16) & 1u)) >> 16;
    return (ushort_t)r;
}

__device__ __forceinline__ float bf2f(ushort_t u) {
    return __uint_as_float(((unsigned int)u) << 16);
}

__device__ __forceinline__ unsigned int fkey(float f) {
    unsigned int u = __float_as_uint(f);
    return (u & 0x80000000u) ? ~u : (u | 0x80000000u);
}
__device__ __forceinline__ float funkey(unsigned int k) {
    unsigned int u = (k & 0x80000000u) ? (k & 0x7fffffffu) : ~k;
    return __uint_as_float(u);
}

// async global->LDS 16B per lane; LDS dest = wave-uniform base + lane*16
__device__ __forceinline__ void gl_lds16(const void* g, void* l) {
    __builtin_amdgcn_global_load_lds(
        (const __attribute__((address_space(1))) unsigned int*)g,
        (__attribute__((address_space(3))) unsigned int*)l, 16, 0, 0);
}

__global__ __launch_bounds__(256) void zero_kernel(float* __restrict__ p, int n) {
    int i = blockIdx.x * 256 + threadIdx.x;
    if (i < n) p[i] = 0.f;
}

// ---------------- LayerNorm -> bf16 out: one wave per 512-float row ----------------
__global__ __launch_bounds__(256) void ln_bf16_kernel(const float* __restrict__ x,
                                                      const float* __restrict__ g,
                                                      const float* __restrict__ b,
                                                      ushort_t* __restrict__ out) {
    int row = blockIdx.x * 4 + (threadIdx.x >> 6);
    int lane = threadIdx.x & 63;
    const float4* xr = (const float4*)(x + (size_t)row * DIMX);
    float4 v0 = xr[lane];
    float4 v1 = xr[lane + 64];
    float sum = v0.x + v0.y + v0.z + v0.w + v1.x + v1.y + v1.z + v1.w;
#pragma unroll
    for (int off = 32; off; off >>= 1) sum += __shfl_xor(sum, off);
    float mu = sum * (1.0f / 512.0f);
    float var = (v0.x - mu) * (v0.x - mu) + (v0.y - mu) * (v0.y - mu) +
                (v0.z - mu) * (v0.z - mu) + (v0.w - mu) * (v0.w - mu) +
                (v1.x - mu) * (v1.x - mu) + (v1.y - mu) * (v1.y - mu) +
                (v1.z - mu) * (v1.z - mu) + (v1.w - mu) * (v1.w - mu);
#pragma unroll
    for (int off = 32; off; off >>= 1) var += __shfl_xor(var, off);
    float rstd = rsqrtf(var * (1.0f / 512.0f) + 1e-5f);
    const float4* g4 = (const float4*)g;
    const float4* b4 = (const float4*)b;
    ushort_t* orow = out + (size_t)row * DIMX;
    float4 gg = g4[lane], bb = b4[lane];
    ushort4 o;
    o.x = f2bf((v0.x - mu) * rstd * gg.x + bb.x);
    o.y = f2bf((v0.y - mu) * rstd * gg.y + bb.y);
    o.z = f2bf((v0.z - mu) * rstd * gg.z + bb.z);
    o.w = f2bf((v0.w - mu) * rstd * gg.w + bb.w);
    *(ushort4*)(orow + lane * 4) = o;
    gg = g4[lane + 64]; bb = b4[lane + 64];
    o.x = f2bf((v1.x - mu) * rstd * gg.x + bb.x);
    o.y = f2bf((v1.y - mu) * rstd * gg.y + bb.y);
    o.z = f2bf((v1.z - mu) * rstd * gg.z + bb.z);
    o.w = f2bf((v1.w - mu) * rstd * gg.w + bb.w);
    *(ushort4*)(orow + 256 + lane * 4) = o;
}

// ---------------- weight transpose-convert: W[K,N] fp32 -> Wt[N,K] bf16 ----------------
__global__ __launch_bounds__(256) void wconv_kernel(const float* __restrict__ W,
                                                    ushort_t* __restrict__ Wt,
                                                    int K, int N) {
    __shared__ float tile[32][33];
    int bx = blockIdx.x * 32;  // n
    int by = blockIdx.y * 32;  // k
    int tx = threadIdx.x & 31, ty = threadIdx.x >> 5;
#pragma unroll
    for (int r = 0; r < 4; r++)
        tile[ty + r * 8][tx] = W[(size_t)(by + ty + r * 8) * N + bx + tx];
    __syncthreads();
#pragma unroll
    for (int r = 0; r < 4; r++)
        Wt[(size_t)(bx + ty + r * 8) * K + by + tx] = f2bf(tile[tx][ty + r * 8]);
}

// 4 square 512x512 weights in one launch (grid.z selects)
__global__ __launch_bounds__(256) void wconv4_kernel(const float* __restrict__ W0,
                                                     const float* __restrict__ W1,
                                                     const float* __restrict__ W2,
                                                     const float* __restrict__ W3,
                                                     ushort_t* __restrict__ Wt) {
    __shared__ float tile[32][33];
    const float* Ws[4] = {W0, W1, W2, W3};
    const float* W = Ws[blockIdx.z];
    ushort_t* Wd = Wt + (size_t)blockIdx.z * DIMX * DIMX;
    int bx = blockIdx.x * 32;
    int by = blockIdx.y * 32;
    int tx = threadIdx.x & 31, ty = threadIdx.x >> 5;
#pragma unroll
    for (int r = 0; r < 4; r++)
        tile[ty + r * 8][tx] = W[(size_t)(by + ty + r * 8) * DIMX + bx + tx];
    __syncthreads();
#pragma unroll
    for (int r = 0; r < 4; r++)
        Wd[(size_t)(bx + ty + r * 8) * DIMX + by + tx] = f2bf(tile[tx][ty + r * 8]);
}

// ---------------- proj fp32 [266][64] -> bf16 [288][64] (pad rows zero) ----------------
__global__ __launch_bounds__(256) void projconv_kernel(const float* __restrict__ proj,
                                                       ushort_t* __restrict__ Pbf) {
    int i = blockIdx.x * 256 + threadIdx.x;
    if (i < MP * DHE) {
        int m = i >> 6;
        Pbf[i] = (m < NB) ? f2bf(proj[i]) : (ushort_t)0;
    }
}

// ---------------- bf16 MFMA GEMM: 128x128 tile, 16x16x32, m97 structure ----------------
// A[M,K] bf16 row-major; Bt[N,K] bf16 row-major.
// EPI 1: C += A@B + bias (fp32). EPI 2: Cb = bf16(gelu(A@B+bias)).
// EPI 4: transposed per-head bf16: Vt[(b*8+h)*64+d][8192].
// EPI 5: Cb = bf16(A@B) and SS[head][row] = sum over head cols of v^2.
template <int EPI>
__global__ __launch_bounds__(256) void gemm_mfma(const ushort_t* __restrict__ A,
                                                 const ushort_t* __restrict__ Bt,
                                                 const float* __restrict__ bias,
                                                 float* __restrict__ C,
                                                 ushort_t* __restrict__ Cb,
                                                 float* __restrict__ SS,
                                                 int M, int N, int K) {
    __shared__ ushort_t As[128 * 32];
    __shared__ ushort_t Bs[128 * 32];
    int t = threadIdx.x;
    int wave = t >> 6, lane = t & 63;
    int wm = wave >> 1, wn = wave & 1;
    int m0 = blockIdx.x * 128, n0 = blockIdx.y * 128;
    int q = lane >> 4, ml = lane & 15;

    floatx4 acc[4][4];
#pragma unroll
    for (int i = 0; i < 4; i++)
#pragma unroll
        for (int j = 0; j < 4; j++) acc[i][j] = (floatx4)(0.f);

    int srow = (lane >> 2);
    int scol = (lane & 3) * 8;
    const ushort_t* Ag = A + (size_t)(m0 + wave * 32 + srow) * K + scol;
    const ushort_t* Bg = Bt + (size_t)(n0 + wave * 32 + srow) * K + scol;
    ushort_t* AsW = &As[(wave * 32) * 32];
    ushort_t* BsW = &Bs[(wave * 32) * 32];

    for (int k0 = 0; k0 < K; k0 += 32) {
        gl_lds16(Ag + k0, AsW);
        gl_lds16(Ag + k0 + (size_t)16 * K, AsW + 16 * 32);
        gl_lds16(Bg + k0, BsW);
        gl_lds16(Bg + k0 + (size_t)16 * K, BsW + 16 * 32);
        __syncthreads();
        short8 a[4], b[4];
#pragma unroll
        for (int i = 0; i < 4; i++)
            a[i] = *(const short8*)&As[(wm * 64 + i * 16 + ml) * 32 + q * 8];
#pragma unroll
        for (int j = 0; j < 4; j++)
            b[j] = *(const short8*)&Bs[(wn * 64 + j * 16 + ml) * 32 + q * 8];
#pragma unroll
        for (int i = 0; i < 4; i++)
#pragma unroll
            for (int j = 0; j < 4; j++)
                acc[i][j] = __builtin_amdgcn_mfma_f32_16x16x32_bf16(a[i], b[j], acc[i][j], 0, 0, 0);
        __syncthreads();
    }

    if (EPI == 4) {
#pragma unroll
        for (int i = 0; i < 4; i++) {
            size_t r0 = (size_t)m0 + wm * 64 + i * 16 + q * 4;
            int bb = (int)(r0 >> 13);
            int nl = (int)(r0 & (SEQ - 1));
#pragma unroll
            for (int j = 0; j < 4; j++) {
                int col = n0 + wn * 64 + j * 16 + ml;
                int hh = col >> 6, dd = col & 63;
                ushort4 pk;
                pk.x = f2bf(acc[i][j][0]); pk.y = f2bf(acc[i][j][1]);
                pk.z = f2bf(acc[i][j][2]); pk.w = f2bf(acc[i][j][3]);
                *(ushort4*)&Cb[(((size_t)bb * 8 + hh) * DHE + dd) * SEQ + nl] = pk;
            }
        }
    } else if (EPI == 5) {
        int hh = (n0 >> 6) + wn;  // each wave's 64 cols = one head
#pragma unroll
        for (int i = 0; i < 4; i++) {
#pragma unroll
            for (int r = 0; r < 4; r++) {
                size_t row = (size_t)m0 + wm * 64 + i * 16 + q * 4 + r;
                float sq = 0.f;
#pragma unroll
                for (int j = 0; j < 4; j++) {
                    int col = n0 + wn * 64 + j * 16 + ml;
                    float v = acc[i][j][r];
                    sq += v * v;
                    Cb[row * N + col] = f2bf(v);
                }
                sq += __shfl_xor(sq, 1);
                sq += __shfl_xor(sq, 2);
                sq += __shfl_xor(sq, 4);
                sq += __shfl_xor(sq, 8);
                if (ml == 0) SS[(size_t)hh * PSEQ + row] = sq;
            }
        }
    } else {
#pragma unroll
        for (int i = 0; i < 4; i++) {
#pragma unroll
            for (int r = 0; r < 4; r++) {
                size_t row = (size_t)m0 + wm * 64 + i * 16 + q * 4 + r;
#pragma unroll
                for (int j = 0; j < 4; j++) {
                    int col = n0 + wn * 64 + j * 16 + ml;
                    float v = acc[i][j][r];
                    if (EPI == 1) {
                        C[row * N + col] += v + bias[col];
                    } else if (EPI == 2) {
                        Cb[row * N + col] = f2bf(gelu_f(v + bias[col]));
                    }
                }
            }
        }
    }
}

// ---------------- fp32 VALU GEMM (final fc, N=32) ----------------
template <int DOACC, int DOGELU>
__global__ __launch_bounds__(256) void gemm_kernel(const float* __restrict__ A,
                                                   const float* __restrict__ B,
                                                   const float* __restrict__ bias,
                                                   float* __restrict__ C,
                                                   int M, int N, int K) {
    __shared__ float As[16][132];
    __shared__ float Bs[16][132];
    int t = threadIdx.x;
    int tx = t & 15, ty = t >> 4;
    int m0 = blockIdx.x * 128;
    int n0 = blockIdx.y * 128;
    float c[8][8];
#pragma unroll
    for (int i = 0; i < 8; i++)
#pragma unroll
        for (int j = 0; j < 8; j++) c[i][j] = 0.f;
    int am = t >> 1;
    int ak = (t & 1) * 8;
    const float* Aptr = A + (size_t)(m0 + am) * K + ak;
    int bn = (t & 15) * 8;
    int bk = t >> 4;
    bool bvalid = (n0 + bn) < N;
    const float* Bptr = B + (size_t)bk * N + n0 + bn;
    for (int k0 = 0; k0 < K; k0 += 16) {
        float4 a0 = *(const float4*)(Aptr + k0);
        float4 a1 = *(const float4*)(Aptr + k0 + 4);
        As[ak + 0][am] = a0.x; As[ak + 1][am] = a0.y;
        As[ak + 2][am] = a0.z; As[ak + 3][am] = a0.w;
        As[ak + 4][am] = a1.x; As[ak + 5][am] = a1.y;
        As[ak + 6][am] = a1.z; As[ak + 7][am] = a1.w;
        float4 b0 = make_float4(0.f, 0.f, 0.f, 0.f);
        float4 b1v = make_float4(0.f, 0.f, 0.f, 0.f);
        if (bvalid) {
            const float* bp = Bptr + (size_t)k0 * N;
            b0 = *(const float4*)bp;
            b1v = *(const float4*)(bp + 4);
        }
        *(float4*)&Bs[bk][bn] = b0;
        *(float4*)&Bs[bk][bn + 4] = b1v;
        __syncthreads();
#pragma unroll
        for (int kk = 0; kk < 16; kk++) {
            float4 av0 = *(const float4*)&As[kk][ty * 4];
            float4 av1 = *(const float4*)&As[kk][64 + ty * 4];
            float4 bv0 = *(const float4*)&Bs[kk][tx * 4];
            float4 bv1 = *(const float4*)&Bs[kk][64 + tx * 4];
            float a_[8] = {av0.x, av0.y, av0.z, av0.w, av1.x, av1.y, av1.z, av1.w};
            float b_[8] = {bv0.x, bv0.y, bv0.z, bv0.w, bv1.x, bv1.y, bv1.z, bv1.w};
#pragma unroll
            for (int i = 0; i < 8; i++)
#pragma unroll
                for (int j = 0; j < 8; j++) c[i][j] += a_[i] * b_[j];
        }
        __syncthreads();
    }
#pragma unroll
    for (int ih = 0; ih < 2; ih++)
#pragma unroll
        for (int il = 0; il < 4; il++) {
            size_t row = (size_t)m0 + ih * 64 + ty * 4 + il;
#pragma unroll
            for (int jh = 0; jh < 2; jh++) {
                int colbase = n0 + jh * 64 + tx * 4;
                if (colbase < N) {
                    float* cp = C + row * N + colbase;
#pragma unroll
                    for (int jl = 0; jl < 4; jl++) {
                        float v = c[ih * 4 + il][jh * 4 + jl];
                        if (bias) v += bias[colbase + jl];
                        if (DOGELU) v = gelu_f(v);
                        if (DOACC) v += cp[jl];
                        cp[jl] = v;
                    }
                }
            }
        }
}

// ---------------- global key-feature max via MFMA: grid (128 tiles x 8 heads) ----------------
__global__ __launch_bounds__(512) void kmax_kernel(const ushort_t* __restrict__ Kbf,
                                                   const ushort_t* __restrict__ Pbf,
                                                   unsigned int* __restrict__ kmaxkey) {
    int tid = threadIdx.x;
    int w = tid >> 6, lane = tid & 63;
    int q = lane >> 4, ml = lane & 15;
    int h = blockIdx.x >> 7, tile = blockIdx.x & 127;
    int arow = tile * 128 + w * 16 + ml;
    short8 af0 = *(const short8*)&Kbf[(size_t)arow * DIMX + h * DHE + q * 8];
    short8 af1 = *(const short8*)&Kbf[(size_t)arow * DIMX + h * DHE + 32 + q * 8];
    float lm = -3.0e38f;
#pragma unroll
    for (int c = 0; c < 17; c++) {
        floatx4 xp = (floatx4)(0.f);
        short8 b0 = *(const short8*)&Pbf[(c * 16 + ml) * DHE + q * 8];
        short8 b1 = *(const short8*)&Pbf[(c * 16 + ml) * DHE + 32 + q * 8];
        xp = __builtin_amdgcn_mfma_f32_16x16x32_bf16(af0, b0, xp, 0, 0, 0);
        xp = __builtin_amdgcn_mfma_f32_16x16x32_bf16(af1, b1, xp, 0, 0, 0);
        if (c * 16 + ml < NB)
            lm = fmaxf(lm, fmaxf(fmaxf(xp[0], xp[1]), fmaxf(xp[2], xp[3])));
    }
    lm *= DN_F;
#pragma unroll
    for (int off = 32; off; off >>= 1) lm = fmaxf(lm, __shfl_xor(lm, off));
    if (lane == 0) atomicMax(kmaxkey, fkey(lm));
}

// ---------------- fused kp + CTX partial via MFMA (half-split kpT, 2 blocks/CU) ------------
// grid 512 = 16 bh x 32 strips of 256 tokens (2 sub-tiles of 128); 8 waves.
// CTXP [16bh][32 strips][288][64] f32 partials; KSUM [16bh][288] atomic f32.
__global__ __launch_bounds__(512, 4) void kctx_kernel(const ushort_t* __restrict__ Kbf,
                                                      const ushort_t* __restrict__ Pbf,
                                                      const float* __restrict__ SS,
                                                      const unsigned int* __restrict__ kmaxkey,
                                                      const ushort_t* __restrict__ Vt,
                                                      float* __restrict__ CTXP,
                                                      float* __restrict__ KSUM) {
    __shared__ ushort_t kpT[144 * KPT_LD];   // half of m-range: 39168 B
    __shared__ float ksum_l[MP];
    int tid = threadIdx.x;
    int w = tid >> 6, lane = tid & 63;
    int q = lane >> 4, ml = lane & 15;
    int bh = blockIdx.x >> 5, s = blockIdx.x & 31;
    int b = bh >> 3, h = bh & 7;
    float mx = funkey(*kmaxkey);
    if (tid < MP) ksum_l[tid] = 0.f;
    __syncthreads();
    floatx4 ctxa[2][5];
#pragma unroll
    for (int hf = 0; hf < 2; hf++)
#pragma unroll
        for (int i = 0; i < 5; i++) ctxa[hf][i] = (floatx4)(0.f);

#pragma unroll
    for (int sub = 0; sub < 2; sub++) {
        int tb = b * SEQ + s * 256 + sub * 128;
        int arow = tb + w * 16 + ml;
        short8 af0 = *(const short8*)&Kbf[(size_t)arow * DIMX + h * DHE + q * 8];
        short8 af1 = *(const short8*)&Kbf[(size_t)arow * DIMX + h * DHE + 32 + q * 8];
        float ssr[4];
#pragma unroll
        for (int r = 0; r < 4; r++) ssr[r] = SS[h * PSEQ + tb + w * 16 + q * 4 + r];
#pragma unroll
        for (int hf = 0; hf < 2; hf++) {
            // --- XP phase for m = hf*144 .. hf*144+143 ---
#pragma unroll
            for (int cl = 0; cl < 9; cl++) {
                int c = hf * 9 + cl;
                floatx4 xp = (floatx4)(0.f);
                short8 b0 = *(const short8*)&Pbf[(c * 16 + ml) * DHE + q * 8];
                short8 b1 = *(const short8*)&Pbf[(c * 16 + ml) * DHE + 32 + q * 8];
                xp = __builtin_amdgcn_mfma_f32_16x16x32_bf16(af0, b0, xp, 0, 0, 0);
                xp = __builtin_amdgcn_mfma_f32_16x16x32_bf16(af1, b1, xp, 0, 0, 0);
                int m = c * 16 + ml;
                bool val = m < NB;
                float kpv[4];
#pragma unroll
                for (int r = 0; r < 4; r++)
                    kpv[r] = val ? RATIO_F * (__expf(xp[r] * DN_F - ssr[r] * 0.0625f - mx) + EPS_F)
                                 : 0.f;
                ushort4 pk;
                pk.x = f2bf(kpv[0]); pk.y = f2bf(kpv[1]);
                pk.z = f2bf(kpv[2]); pk.w = f2bf(kpv[3]);
                *(ushort4*)&kpT[(cl * 16 + ml) * KPT_LD + w * 16 + q * 4] = pk;
                float s4 = kpv[0] + kpv[1] + kpv[2] + kpv[3];
                s4 += __shfl_xor(s4, 16);
                s4 += __shfl_xor(s4, 32);
                if (q == 0) atomicAdd(&ksum_l[m], s4);
            }
            __syncthreads();
            // --- CTX phase: 36 tiles (9 mt x 4 dt) over 8 waves ---
#pragma unroll
            for (int sk = 0; sk < 4; sk++) {
#pragma unroll
                for (int i = 0; i < 5; i++) {
                    if (i < 4 || w < 4) {
                        int tt = w + i * 8;
                        int mtl = tt >> 2, dt = tt & 3;
                        short8 a = *(const short8*)&kpT[(mtl * 16 + ml) * KPT_LD + sk * 32 + q * 8];
                        short8 bv = *(const short8*)&Vt[((size_t)bh * DHE + dt * 16 + ml) * SEQ +
                                                        s * 256 + sub * 128 + sk * 32 + q * 8];
                        ctxa[hf][i] = __builtin_amdgcn_mfma_f32_16x16x32_bf16(a, bv, ctxa[hf][i], 0, 0, 0);
                    }
                }
            }
            __syncthreads();
        }
    }
    float* cp = CTXP + ((size_t)bh * NSTRIP + s) * (MP * DHE);
#pragma unroll
    for (int hf = 0; hf < 2; hf++) {
#pragma unroll
        for (int i = 0; i < 5; i++) {
            if (i < 4 || w < 4) {
                int tt = w + i * 8;
                int mt = hf * 9 + (tt >> 2);
                int dt = tt & 3;
#pragma unroll
                for (int r = 0; r < 4; r++)
                    cp[(mt * 16 + q * 4 + r) * DHE + dt * 16 + ml] = ctxa[hf][i][r];
            }
        }
    }
    if (tid < MP) atomicAdd(&KSUM[bh * MP + tid], ksum_l[tid]);
}

// ---------------- reduce CTX partials over 32 strips ----------------
__global__ __launch_bounds__(256) void ctx_reduce_kernel(const float* __restrict__ CTXP,
                                                         float* __restrict__ CTX) {
    int i = blockIdx.x * 256 + threadIdx.x;  // 16*288*64
    if (i < 16 * MP * DHE) {
        int bh = i / (MP * DHE);
        int e = i - bh * (MP * DHE);
        float s = 0.f;
#pragma unroll
        for (int st = 0; st < NSTRIP; st++)
            s += CTXP[((size_t)bh * NSTRIP + st) * (MP * DHE) + e];
        CTX[i] = s;
    }
}

// ---------------- fused qp + rowmax + denom + O = dinv*(qp@CTX) via MFMA ----------------
// grid 2048 = 16 bh x 128 tiles of 64 tokens; 4 waves; 3 blocks/CU.
__global__ __launch_bounds__(256, 3) void qo_kernel(const ushort_t* __restrict__ Qbf,
                                                    const ushort_t* __restrict__ Pbf,
                                                    const float* __restrict__ SS,
                                                    const float* __restrict__ CTX,
                                                    const float* __restrict__ KSUM,
                                                    ushort_t* __restrict__ Ob) {
    __shared__ ushort_t ctxt[DHE * CTXT_LD];   // CTX^T bf16 [d][m], 37888 B
    __shared__ ushort_t qpA[4][16][40];        // per-wave qp chunk (no barriers needed)
    __shared__ float ksl[MP];
    int tid = threadIdx.x;
    int w = tid >> 6, lane = tid & 63;
    int q = lane >> 4, ml = lane & 15;
    int bh = blockIdx.x >> 7, tile = blockIdx.x & 127;
    int b = bh >> 3, h = bh & 7;
    const float4* C4 = (const float4*)(CTX + (size_t)bh * (MP * DHE));
#pragma unroll
    for (int it = 0; it < 18; it++) {
        int e4 = tid + it * 256;               // 0..4607
        int m = e4 >> 4, d0 = (e4 & 15) * 4;
        float4 v = C4[e4];
        ctxt[(d0 + 0) * CTXT_LD + m] = f2bf(v.x);
        ctxt[(d0 + 1) * CTXT_LD + m] = f2bf(v.y);
        ctxt[(d0 + 2) * CTXT_LD + m] = f2bf(v.z);
        ctxt[(d0 + 3) * CTXT_LD + m] = f2bf(v.w);
    }
    ksl[tid] = KSUM[bh * MP + tid];
    if (tid < MP - 256) ksl[256 + tid] = KSUM[bh * MP + 256 + tid];
    __syncthreads();
    int nl = tile * 64 + w * 16;
    int arow = b * SEQ + nl + ml;
    short8 af0 = *(const short8*)&Qbf[(size_t)arow * DIMX + h * DHE + q * 8];
    short8 af1 = *(const short8*)&Qbf[(size_t)arow * DIMX + h * DHE + 32 + q * 8];
    floatx4 xp[MT];
#pragma unroll
    for (int c = 0; c < MT; c++) {
        xp[c] = (floatx4)(0.f);
        short8 b0 = *(const short8*)&Pbf[(c * 16 + ml) * DHE + q * 8];
        short8 b1 = *(const short8*)&Pbf[(c * 16 + ml) * DHE + 32 + q * 8];
        xp[c] = __builtin_amdgcn_mfma_f32_16x16x32_bf16(af0, b0, xp[c], 0, 0, 0);
        xp[c] = __builtin_amdgcn_mfma_f32_16x16x32_bf16(af1, b1, xp[c], 0, 0, 0);
    }
    float ssr[4], rm[4], dp[4], dinv[4];
#pragma unroll
    for (int r = 0; r < 4; r++) {
        ssr[r] = SS[h * PSEQ + b * SEQ + nl + q * 4 + r];
        rm[r] = -3.0e38f;
        dp[r] = 0.f;
    }
#pragma unroll
    for (int c = 0; c < MT; c++) {
        int m = c * 16 + ml;
        bool val = m < NB;
#pragma unroll
        for (int r = 0; r < 4; r++) {
            float tv = xp[c][r] * DN_F;
            xp[c][r] = tv;
            if (val) rm[r] = fmaxf(rm[r], tv);
        }
    }
#pragma unroll
    for (int r = 0; r < 4; r++) {
        rm[r] = fmaxf(rm[r], __shfl_xor(rm[r], 1));
        rm[r] = fmaxf(rm[r], __shfl_xor(rm[r], 2));
        rm[r] = fmaxf(rm[r], __shfl_xor(rm[r], 4));
        rm[r] = fmaxf(rm[r], __shfl_xor(rm[r], 8));
    }
#pragma unroll
    for (int c = 0; c < MT; c++) {
        int m = c * 16 + ml;
        bool val = m < NB;
        float km = ksl[m];
#pragma unroll
        for (int r = 0; r < 4; r++) {
            float v = val ? RATIO_F * (__expf(xp[c][r] - ssr[r] * 0.0625f - rm[r]) + EPS_F) : 0.f;
            xp[c][r] = v;
            dp[r] += v * km;
        }
    }
#pragma unroll
    for (int r = 0; r < 4; r++) {
        dp[r] += __shfl_xor(dp[r], 1);
        dp[r] += __shfl_xor(dp[r], 2);
        dp[r] += __shfl_xor(dp[r], 4);
        dp[r] += __shfl_xor(dp[r], 8);
        dinv[r] = 1.0f / dp[r];
    }
    floatx4 oacc[4];
#pragma unroll
    for (int dt = 0; dt < 4; dt++) oacc[dt] = (floatx4)(0.f);
#pragma unroll
    for (int ks = 0; ks < 9; ks++) {
#pragma unroll
        for (int cc = 0; cc < 2; cc++) {
            int c = 2 * ks + cc;
#pragma unroll
            for (int r = 0; r < 4; r++)
                qpA[w][q * 4 + r][cc * 16 + ml] = f2bf(xp[c][r]);
        }
        // per-wave LDS RAW: DS ops are in-order within a wave; no block barrier needed
        short8 a = *(const short8*)&qpA[w][ml][q * 8];
#pragma unroll
        for (int dt = 0; dt < 4; dt++) {
            short8 bv = *(const short8*)&ctxt[(dt * 16 + ml) * CTXT_LD + ks * 32 + q * 8];
            oacc[dt] = __builtin_amdgcn_mfma_f32_16x16x32_bf16(a, bv, oacc[dt], 0, 0, 0);
        }
    }
#pragma unroll
    for (int dt = 0; dt < 4; dt++)
#pragma unroll
        for (int r = 0; r < 4; r++)
            Ob[(size_t)(b * SEQ + nl + q * 4 + r) * DIMX + h * DHE + dt * 16 + ml] =
                f2bf(oacc[dt][r] * dinv[r]);
}

extern "C" void kernel_launch(void* const* d_in, const int* in_sizes, int n_in,
                              void* d_out, int out_size, void* d_ws, size_t ws_size,
                              hipStream_t stream) {
    (void)in_sizes; (void)n_in; (void)out_size; (void)ws_size;
    const float* src  = (const float*)d_in[0];
    const float* proj = (const float*)d_in[1];
    const float* ln1g = (const float*)d_in[2];
    const float* ln1b = (const float*)d_in[3];
    const float* Wq   = (const float*)d_in[4];
    const float* Wk   = (const float*)d_in[5];
    const float* Wv   = (const float*)d_in[6];
    const float* Wo   = (const float*)d_in[7];
    const float* bo   = (const float*)d_in[8];
    const float* ln2g = (const float*)d_in[9];
    const float* ln2b = (const float*)d_in[10];
    const float* W1   = (const float*)d_in[11];
    const float* b1   = (const float*)d_in[12];
    const float* W2   = (const float*)d_in[13];
    const float* b2   = (const float*)d_in[14];
    const float* fcw  = (const float*)d_in[15];
    const float* fcb  = (const float*)d_in[16];
    float* out = (float*)d_out;

    // ---- workspace layout (~157.4 MiB of 162 safe) ----
    const size_t TD   = (size_t)NTOK * DIMX;
    const size_t PD   = (size_t)PSEQ * DIMX;
    float*    X    = (float*)d_ws;                      // 64 MiB residual fp32
    ushort_t* Hs   = (ushort_t*)(X + TD);               // 16 MiB LN out bf16 (pair)
    ushort_t* KQbf = Hs + PD;                           // 16 MiB K bf16, then Q bf16
    ushort_t* Vt   = KQbf + PD;                         // 16 MiB V^T per-head bf16
    float*    CTXP = (float*)(Vt + PD);                 // 37.75 MiB ctx partials (32 strips)
    ushort_t* Obuf = (ushort_t*)CTXP;                   // 16 MiB attn-out bf16, aliases CTXP
    float*    CTX  = CTXP + (size_t)16 * NSTRIP * MP * DHE;  // 1.125 MiB
    float*    KSUM = CTX + (size_t)16 * MP * DHE;       // 16x288
    unsigned int* KMAX = (unsigned int*)(KSUM + 16 * MP);
    float*    SS   = (float*)(KMAX + 4);                // [8][PSEQ]
    ushort_t* Pbf  = (ushort_t*)(SS + (size_t)NHEADS * PSEQ);  // [288][64] bf16
    ushort_t* Wtb  = Pbf + MP * DHE;                    // 6 MiB weights bf16
    ushort_t* Wqt = Wtb;
    ushort_t* Wkt = Wqt + DIMX * DIMX;
    ushort_t* Wvt = Wkt + DIMX * DIMX;
    ushort_t* Wot = Wvt + DIMX * DIMX;
    ushort_t* W1t = Wot + DIMX * DIMX;         // [FFD, DIMX]
    ushort_t* W2t = W1t + (size_t)DIMX * FFD;  // [DIMX, FFD]
    ushort_t* Hid = KQbf;  // FF hidden 64 MiB: aliases KQbf+Vt+CTXP head (all dead in FF)

    hipMemcpyAsync(X, src, sizeof(float) * TD, hipMemcpyDeviceToDevice, stream);

    dim3 gP(PSEQ / 128, DIMX / 128);   // (128,4)
    dim3 gF1(PSEQ / 128, FFD / 128);   // (128,16)
    const int lnGrid = PSEQ / 4;       // 4096
    for (int L = 0; L < NLAYER; L++) {
        const float* pj = proj + (size_t)L * NB * DHE;
        wconv4_kernel<<<dim3(16, 16, 4), 256, 0, stream>>>(
            Wq + (size_t)L * DIMX * DIMX, Wk + (size_t)L * DIMX * DIMX,
            Wv + (size_t)L * DIMX * DIMX, Wo + (size_t)L * DIMX * DIMX, Wqt);
        wconv_kernel<<<dim3(64, 16), 256, 0, stream>>>(W1 + (size_t)L * DIMX * FFD, W1t, DIMX, FFD);
        wconv_kernel<<<dim3(16, 64), 256, 0, stream>>>(W2 + (size_t)L * FFD * DIMX, W2t, FFD, DIMX);
        projconv_kernel<<<(MP * DHE + 255) / 256, 256, 0, stream>>>(pj, Pbf);
        zero_kernel<<<1, 256, 0, stream>>>((float*)KMAX, 1);
        // --- phase A: global key-feature max over both pairs ---
        for (int p = 0; p < 2; p++) {
            const float* Xp = X + (size_t)p * PD;
            ln_bf16_kernel<<<lnGrid, 256, 0, stream>>>(Xp, ln1g + L * DIMX, ln1b + L * DIMX, Hs);
            gemm_mfma<5><<<gP, 256, 0, stream>>>(Hs, Wkt, nullptr, nullptr, KQbf, SS, PSEQ, DIMX, DIMX);
            kmax_kernel<<<1024, 512, 0, stream>>>(KQbf, Pbf, KMAX);
        }
        // --- phase B: attention + FF per pair (p=1 first: Hs/KQbf/SS still hold pair-1) ---
        for (int pp = 0; pp < 2; pp++) {
            int p = 1 - pp;
            float* Xp = X + (size_t)p * PD;
            if (p == 0) {
                ln_bf16_kernel<<<lnGrid, 256, 0, stream>>>(Xp, ln1g + L * DIMX, ln1b + L * DIMX, Hs);
                gemm_mfma<5><<<gP, 256, 0, stream>>>(Hs, Wkt, nullptr, nullptr, KQbf, SS, PSEQ, DIMX, DIMX);
            }
            gemm_mfma<4><<<gP, 256, 0, stream>>>(Hs, Wvt, nullptr, nullptr, Vt, nullptr, PSEQ, DIMX, DIMX);
            zero_kernel<<<(16 * MP + 255) / 256, 256, 0, stream>>>(KSUM, 16 * MP);
            kctx_kernel<<<16 * NSTRIP, 512, 0, stream>>>(KQbf, Pbf, SS, KMAX, Vt, CTXP, KSUM);
            ctx_reduce_kernel<<<(16 * MP * DHE + 255) / 256, 256, 0, stream>>>(CTXP, CTX);
            gemm_mfma<5><<<gP, 256, 0, stream>>>(Hs, Wqt, nullptr, nullptr, KQbf, SS, PSEQ, DIMX, DIMX);
            qo_kernel<<<2048, 256, 0, stream>>>(KQbf, Pbf, SS, CTX, KSUM, Obuf);
            gemm_mfma<1><<<gP, 256, 0, stream>>>(Obuf, Wot, bo + L * DIMX, Xp, nullptr, nullptr, PSEQ, DIMX, DIMX);
            // --- FF ---
            ln_bf16_kernel<<<lnGrid, 256, 0, stream>>>(Xp, ln2g + L * DIMX, ln2b + L * DIMX, Hs);
            gemm_mfma<2><<<gF1, 256, 0, stream>>>(Hs, W1t, b1 + L * FFD, nullptr, Hid, nullptr, PSEQ, FFD, DIMX);
            gemm_mfma<1><<<gP, 256, 0, stream>>>(Hid, W2t, b2 + L * DIMX, Xp, nullptr, nullptr, PSEQ, DIMX, FFD);
        }
    }
    gemm_kernel<0, 0><<<dim3(NTOK / 128, 1), 256, 0, stream>>>(X, fcw, fcb, out, NTOK, OUTD, DIMX);
}

// Round 5
// 5488.478 us; speedup vs baseline: 7.9814x; 1.2043x over previous
//
#include <hip/hip_runtime.h>
#include <math.h>

#define DIMX 512
#define NHEADS 8
#define DHE 64
#define NB 266
#define MP 288          // NB padded to 18 MFMA col-tiles
#define MT 18           // MP/16
#define KPT_LD 136      // kpT row stride (128+8) to break banks
#define CTXT_LD 296     // ctxt row stride (288+8)
#define NSTRIP 32       // strips per (b,h) in kctx
#define FFD 2048
#define OUTD 32
#define SEQ 8192
#define NTOK 32768
#define NLAYER 6
#define PSEQ 16384      // tokens per batch-pair

#define DN_F 0.35355339059327373f
#define RATIO_F 0.06131393f
#define EPS_F 1e-4f

typedef unsigned short ushort_t;
typedef __attribute__((ext_vector_type(8))) short short8;
typedef __attribute__((ext_vector_type(4))) float floatx4;

__device__ __forceinline__ float tanh_fast(float x) {
    float e = __expf(2.0f * x);
    return 1.0f - 2.0f / (e + 1.0f);
}

__device__ __forceinline__ float gelu_f(float x) {
    float x3 = x * x * x;
    return 0.5f * x * (1.0f + tanh_fast(0.7978845608028654f * (x + 0.044715f * x3)));
}

__device__ __forceinline__ ushort_t f2bf(float f) {
    unsigned int u = __float_as_uint(f);
    unsigned int r = (u + 0x7fffu + ((u >> 16) & 1u)) >> 16;
    return (ushort_t)r;
}

__device__ __forceinline__ float bf2f(ushort_t u) {
    return __uint_as_float(((unsigned int)u) << 16);
}

__device__ __forceinline__ unsigned int fkey(float f) {
    unsigned int u = __float_as_uint(f);
    return (u & 0x80000000u) ? ~u : (u | 0x80000000u);
}
__device__ __forceinline__ float funkey(unsigned int k) {
    unsigned int u = (k & 0x80000000u) ? (k & 0x7fffffffu) : ~k;
    return __uint_as_float(u);
}

// async global->LDS 16B per lane; LDS dest = wave-uniform base + lane*16
__device__ __forceinline__ void gl_lds16(const void* g, void* l) {
    __builtin_amdgcn_global_load_lds(
        (const __attribute__((address_space(1))) unsigned int*)g,
        (__attribute__((address_space(3))) unsigned int*)l, 16, 0, 0);
}

__global__ __launch_bounds__(256) void zero_kernel(float* __restrict__ p, int n) {
    int i = blockIdx.x * 256 + threadIdx.x;
    if (i < n) p[i] = 0.f;
}

// ---------------- LayerNorm -> bf16 out: one wave per 512-float row ----------------
__global__ __launch_bounds__(256) void ln_bf16_kernel(const float* __restrict__ x,
                                                      const float* __restrict__ g,
                                                      const float* __restrict__ b,
                                                      ushort_t* __restrict__ out) {
    int row = blockIdx.x * 4 + (threadIdx.x >> 6);
    int lane = threadIdx.x & 63;
    const float4* xr = (const float4*)(x + (size_t)row * DIMX);
    float4 v0 = xr[lane];
    float4 v1 = xr[lane + 64];
    float sum = v0.x + v0.y + v0.z + v0.w + v1.x + v1.y + v1.z + v1.w;
#pragma unroll
    for (int off = 32; off; off >>= 1) sum += __shfl_xor(sum, off);
    float mu = sum * (1.0f / 512.0f);
    float var = (v0.x - mu) * (v0.x - mu) + (v0.y - mu) * (v0.y - mu) +
                (v0.z - mu) * (v0.z - mu) + (v0.w - mu) * (v0.w - mu) +
                (v1.x - mu) * (v1.x - mu) + (v1.y - mu) * (v1.y - mu) +
                (v1.z - mu) * (v1.z - mu) + (v1.w - mu) * (v1.w - mu);
#pragma unroll
    for (int off = 32; off; off >>= 1) var += __shfl_xor(var, off);
    float rstd = rsqrtf(var * (1.0f / 512.0f) + 1e-5f);
    const float4* g4 = (const float4*)g;
    const float4* b4 = (const float4*)b;
    ushort_t* orow = out + (size_t)row * DIMX;
    float4 gg = g4[lane], bb = b4[lane];
    ushort4 o;
    o.x = f2bf((v0.x - mu) * rstd * gg.x + bb.x);
    o.y = f2bf((v0.y - mu) * rstd * gg.y + bb.y);
    o.z = f2bf((v0.z - mu) * rstd * gg.z + bb.z);
    o.w = f2bf((v0.w - mu) * rstd * gg.w + bb.w);
    *(ushort4*)(orow + lane * 4) = o;
    gg = g4[lane + 64]; bb = b4[lane + 64];
    o.x = f2bf((v1.x - mu) * rstd * gg.x + bb.x);
    o.y = f2bf((v1.y - mu) * rstd * gg.y + bb.y);
    o.z = f2bf((v1.z - mu) * rstd * gg.z + bb.z);
    o.w = f2bf((v1.w - mu) * rstd * gg.w + bb.w);
    *(ushort4*)(orow + 256 + lane * 4) = o;
}

// ---------------- weight transpose-convert: W[K,N] fp32 -> Wt[N,K] bf16 ----------------
__global__ __launch_bounds__(256) void wconv_kernel(const float* __restrict__ W,
                                                    ushort_t* __restrict__ Wt,
                                                    int K, int N) {
    __shared__ float tile[32][33];
    int bx = blockIdx.x * 32;  // n
    int by = blockIdx.y * 32;  // k
    int tx = threadIdx.x & 31, ty = threadIdx.x >> 5;
#pragma unroll
    for (int r = 0; r < 4; r++)
        tile[ty + r * 8][tx] = W[(size_t)(by + ty + r * 8) * N + bx + tx];
    __syncthreads();
#pragma unroll
    for (int r = 0; r < 4; r++)
        Wt[(size_t)(bx + ty + r * 8) * K + by + tx] = f2bf(tile[tx][ty + r * 8]);
}

// 4 square 512x512 weights in one launch (grid.z selects)
__global__ __launch_bounds__(256) void wconv4_kernel(const float* __restrict__ W0,
                                                     const float* __restrict__ W1,
                                                     const float* __restrict__ W2,
                                                     const float* __restrict__ W3,
                                                     ushort_t* __restrict__ Wt) {
    __shared__ float tile[32][33];
    const float* Ws[4] = {W0, W1, W2, W3};
    const float* W = Ws[blockIdx.z];
    ushort_t* Wd = Wt + (size_t)blockIdx.z * DIMX * DIMX;
    int bx = blockIdx.x * 32;
    int by = blockIdx.y * 32;
    int tx = threadIdx.x & 31, ty = threadIdx.x >> 5;
#pragma unroll
    for (int r = 0; r < 4; r++)
        tile[ty + r * 8][tx] = W[(size_t)(by + ty + r * 8) * DIMX + bx + tx];
    __syncthreads();
#pragma unroll
    for (int r = 0; r < 4; r++)
        Wd[(size_t)(bx + ty + r * 8) * DIMX + by + tx] = f2bf(tile[tx][ty + r * 8]);
}

// ---------------- proj fp32 [266][64] -> bf16 [288][64] (pad rows zero) ----------------
__global__ __launch_bounds__(256) void projconv_kernel(const float* __restrict__ proj,
                                                       ushort_t* __restrict__ Pbf) {
    int i = blockIdx.x * 256 + threadIdx.x;
    if (i < MP * DHE) {
        int m = i >> 6;
        Pbf[i] = (m < NB) ? f2bf(proj[i]) : (ushort_t)0;
    }
}

// ---------------- bf16 MFMA GEMM: 128x128 tile, 16x16x32, m97 structure ----------------
// A[M,K] bf16 row-major; Bt[N,K] bf16 row-major.
// EPI 1: C += A@B + bias (fp32). EPI 2: Cb = bf16(gelu(A@B+bias)).
// EPI 4: transposed per-head bf16: Vt[(b*8+h)*64+d][8192].
// EPI 5: Cb = bf16(A@B) and SS[head][row] = sum over head cols of v^2.
template <int EPI>
__global__ __launch_bounds__(256) void gemm_mfma(const ushort_t* __restrict__ A,
                                                 const ushort_t* __restrict__ Bt,
                                                 const float* __restrict__ bias,
                                                 float* __restrict__ C,
                                                 ushort_t* __restrict__ Cb,
                                                 float* __restrict__ SS,
                                                 int M, int N, int K) {
    __shared__ ushort_t As[128 * 32];
    __shared__ ushort_t Bs[128 * 32];
    int t = threadIdx.x;
    int wave = t >> 6, lane = t & 63;
    int wm = wave >> 1, wn = wave & 1;
    int m0 = blockIdx.x * 128, n0 = blockIdx.y * 128;
    int q = lane >> 4, ml = lane & 15;

    floatx4 acc[4][4];
#pragma unroll
    for (int i = 0; i < 4; i++)
#pragma unroll
        for (int j = 0; j < 4; j++) acc[i][j] = (floatx4)(0.f);

    int srow = (lane >> 2);
    int scol = (lane & 3) * 8;
    const ushort_t* Ag = A + (size_t)(m0 + wave * 32 + srow) * K + scol;
    const ushort_t* Bg = Bt + (size_t)(n0 + wave * 32 + srow) * K + scol;
    ushort_t* AsW = &As[(wave * 32) * 32];
    ushort_t* BsW = &Bs[(wave * 32) * 32];

    for (int k0 = 0; k0 < K; k0 += 32) {
        gl_lds16(Ag + k0, AsW);
        gl_lds16(Ag + k0 + (size_t)16 * K, AsW + 16 * 32);
        gl_lds16(Bg + k0, BsW);
        gl_lds16(Bg + k0 + (size_t)16 * K, BsW + 16 * 32);
        __syncthreads();
        short8 a[4], b[4];
#pragma unroll
        for (int i = 0; i < 4; i++)
            a[i] = *(const short8*)&As[(wm * 64 + i * 16 + ml) * 32 + q * 8];
#pragma unroll
        for (int j = 0; j < 4; j++)
            b[j] = *(const short8*)&Bs[(wn * 64 + j * 16 + ml) * 32 + q * 8];
#pragma unroll
        for (int i = 0; i < 4; i++)
#pragma unroll
            for (int j = 0; j < 4; j++)
                acc[i][j] = __builtin_amdgcn_mfma_f32_16x16x32_bf16(a[i], b[j], acc[i][j], 0, 0, 0);
        __syncthreads();
    }

    if (EPI == 4) {
#pragma unroll
        for (int i = 0; i < 4; i++) {
            size_t r0 = (size_t)m0 + wm * 64 + i * 16 + q * 4;
            int bb = (int)(r0 >> 13);
            int nl = (int)(r0 & (SEQ - 1));
#pragma unroll
            for (int j = 0; j < 4; j++) {
                int col = n0 + wn * 64 + j * 16 + ml;
                int hh = col >> 6, dd = col & 63;
                ushort4 pk;
                pk.x = f2bf(acc[i][j][0]); pk.y = f2bf(acc[i][j][1]);
                pk.z = f2bf(acc[i][j][2]); pk.w = f2bf(acc[i][j][3]);
                *(ushort4*)&Cb[(((size_t)bb * 8 + hh) * DHE + dd) * SEQ + nl] = pk;
            }
        }
    } else if (EPI == 5) {
        int hh = (n0 >> 6) + wn;  // each wave's 64 cols = one head
#pragma unroll
        for (int i = 0; i < 4; i++) {
#pragma unroll
            for (int r = 0; r < 4; r++) {
                size_t row = (size_t)m0 + wm * 64 + i * 16 + q * 4 + r;
                float sq = 0.f;
#pragma unroll
                for (int j = 0; j < 4; j++) {
                    int col = n0 + wn * 64 + j * 16 + ml;
                    float v = acc[i][j][r];
                    sq += v * v;
                    Cb[row * N + col] = f2bf(v);
                }
                sq += __shfl_xor(sq, 1);
                sq += __shfl_xor(sq, 2);
                sq += __shfl_xor(sq, 4);
                sq += __shfl_xor(sq, 8);
                if (ml == 0) SS[(size_t)hh * PSEQ + row] = sq;
            }
        }
    } else {
#pragma unroll
        for (int i = 0; i < 4; i++) {
#pragma unroll
            for (int r = 0; r < 4; r++) {
                size_t row = (size_t)m0 + wm * 64 + i * 16 + q * 4 + r;
#pragma unroll
                for (int j = 0; j < 4; j++) {
                    int col = n0 + wn * 64 + j * 16 + ml;
                    float v = acc[i][j][r];
                    if (EPI == 1) {
                        C[row * N + col] += v + bias[col];
                    } else if (EPI == 2) {
                        Cb[row * N + col] = f2bf(gelu_f(v + bias[col]));
                    }
                }
            }
        }
    }
}

// ---------------- fp32 VALU GEMM (final fc, N=32) ----------------
template <int DOACC, int DOGELU>
__global__ __launch_bounds__(256) void gemm_kernel(const float* __restrict__ A,
                                                   const float* __restrict__ B,
                                                   const float* __restrict__ bias,
                                                   float* __restrict__ C,
                                                   int M, int N, int K) {
    __shared__ float As[16][132];
    __shared__ float Bs[16][132];
    int t = threadIdx.x;
    int tx = t & 15, ty = t >> 4;
    int m0 = blockIdx.x * 128;
    int n0 = blockIdx.y * 128;
    float c[8][8];
#pragma unroll
    for (int i = 0; i < 8; i++)
#pragma unroll
        for (int j = 0; j < 8; j++) c[i][j] = 0.f;
    int am = t >> 1;
    int ak = (t & 1) * 8;
    const float* Aptr = A + (size_t)(m0 + am) * K + ak;
    int bn = (t & 15) * 8;
    int bk = t >> 4;
    bool bvalid = (n0 + bn) < N;
    const float* Bptr = B + (size_t)bk * N + n0 + bn;
    for (int k0 = 0; k0 < K; k0 += 16) {
        float4 a0 = *(const float4*)(Aptr + k0);
        float4 a1 = *(const float4*)(Aptr + k0 + 4);
        As[ak + 0][am] = a0.x; As[ak + 1][am] = a0.y;
        As[ak + 2][am] = a0.z; As[ak + 3][am] = a0.w;
        As[ak + 4][am] = a1.x; As[ak + 5][am] = a1.y;
        As[ak + 6][am] = a1.z; As[ak + 7][am] = a1.w;
        float4 b0 = make_float4(0.f, 0.f, 0.f, 0.f);
        float4 b1v = make_float4(0.f, 0.f, 0.f, 0.f);
        if (bvalid) {
            const float* bp = Bptr + (size_t)k0 * N;
            b0 = *(const float4*)bp;
            b1v = *(const float4*)(bp + 4);
        }
        *(float4*)&Bs[bk][bn] = b0;
        *(float4*)&Bs[bk][bn + 4] = b1v;
        __syncthreads();
#pragma unroll
        for (int kk = 0; kk < 16; kk++) {
            float4 av0 = *(const float4*)&As[kk][ty * 4];
            float4 av1 = *(const float4*)&As[kk][64 + ty * 4];
            float4 bv0 = *(const float4*)&Bs[kk][tx * 4];
            float4 bv1 = *(const float4*)&Bs[kk][64 + tx * 4];
            float a_[8] = {av0.x, av0.y, av0.z, av0.w, av1.x, av1.y, av1.z, av1.w};
            float b_[8] = {bv0.x, bv0.y, bv0.z, bv0.w, bv1.x, bv1.y, bv1.z, bv1.w};
#pragma unroll
            for (int i = 0; i < 8; i++)
#pragma unroll
                for (int j = 0; j < 8; j++) c[i][j] += a_[i] * b_[j];
        }
        __syncthreads();
    }
#pragma unroll
    for (int ih = 0; ih < 2; ih++)
#pragma unroll
        for (int il = 0; il < 4; il++) {
            size_t row = (size_t)m0 + ih * 64 + ty * 4 + il;
#pragma unroll
            for (int jh = 0; jh < 2; jh++) {
                int colbase = n0 + jh * 64 + tx * 4;
                if (colbase < N) {
                    float* cp = C + row * N + colbase;
#pragma unroll
                    for (int jl = 0; jl < 4; jl++) {
                        float v = c[ih * 4 + il][jh * 4 + jl];
                        if (bias) v += bias[colbase + jl];
                        if (DOGELU) v = gelu_f(v);
                        if (DOACC) v += cp[jl];
                        cp[jl] = v;
                    }
                }
            }
        }
}

// ---------------- global key-feature max via MFMA: grid 512 = 8 heads x 64 tiles ------------
// Block reduce in LDS -> ONE atomic per block (was 8 per wave-block: same-address atomic
// serialization dominated the old kernel: 8192 serialized atomics ~ 110us).
__global__ __launch_bounds__(512) void kmax_kernel(const ushort_t* __restrict__ Kbf,
                                                   const ushort_t* __restrict__ Pbf,
                                                   unsigned int* __restrict__ kmaxkey) {
    __shared__ float wred[8];
    int tid = threadIdx.x;
    int w = tid >> 6, lane = tid & 63;
    int q = lane >> 4, ml = lane & 15;
    int h = blockIdx.x >> 6, tile = blockIdx.x & 63;
    float lm = -3.0e38f;
#pragma unroll
    for (int sub = 0; sub < 2; sub++) {
        int arow = tile * 256 + sub * 128 + w * 16 + ml;
        short8 af0 = *(const short8*)&Kbf[(size_t)arow * DIMX + h * DHE + q * 8];
        short8 af1 = *(const short8*)&Kbf[(size_t)arow * DIMX + h * DHE + 32 + q * 8];
#pragma unroll
        for (int c = 0; c < 17; c++) {
            floatx4 xp = (floatx4)(0.f);
            short8 b0 = *(const short8*)&Pbf[(c * 16 + ml) * DHE + q * 8];
            short8 b1 = *(const short8*)&Pbf[(c * 16 + ml) * DHE + 32 + q * 8];
            xp = __builtin_amdgcn_mfma_f32_16x16x32_bf16(af0, b0, xp, 0, 0, 0);
            xp = __builtin_amdgcn_mfma_f32_16x16x32_bf16(af1, b1, xp, 0, 0, 0);
            if (c * 16 + ml < NB)
                lm = fmaxf(lm, fmaxf(fmaxf(xp[0], xp[1]), fmaxf(xp[2], xp[3])));
        }
    }
    lm *= DN_F;
#pragma unroll
    for (int off = 32; off; off >>= 1) lm = fmaxf(lm, __shfl_xor(lm, off));
    if (lane == 0) wred[w] = lm;
    __syncthreads();
    if (tid == 0) {
        float bm = wred[0];
#pragma unroll
        for (int ww = 1; ww < 8; ww++) bm = fmaxf(bm, wred[ww]);
        atomicMax(kmaxkey, fkey(bm));
    }
}

// ---------------- fused kp + CTX partial via MFMA (half-split kpT, 2 blocks/CU) ------------
// grid 512 = 16 bh x 32 strips of 256 tokens (2 sub-tiles of 128); 8 waves.
// Output staged through LDS -> fully coalesced float4 stores (kills L2 partial-line RMW).
__global__ __launch_bounds__(512, 4) void kctx_kernel(const ushort_t* __restrict__ Kbf,
                                                      const ushort_t* __restrict__ Pbf,
                                                      const float* __restrict__ SS,
                                                      const unsigned int* __restrict__ kmaxkey,
                                                      const ushort_t* __restrict__ Vt,
                                                      float* __restrict__ CTXP,
                                                      float* __restrict__ KSUM) {
    __shared__ ushort_t kpT[144 * KPT_LD];   // 39168 B; reused as float[144][68] for output
    __shared__ float ksum_l[MP];
    int tid = threadIdx.x;
    int w = tid >> 6, lane = tid & 63;
    int q = lane >> 4, ml = lane & 15;
    int bh = blockIdx.x >> 5, s = blockIdx.x & 31;
    int b = bh >> 3, h = bh & 7;
    float mx = funkey(*kmaxkey);
    if (tid < MP) ksum_l[tid] = 0.f;
    __syncthreads();
    floatx4 ctxa[2][5];
#pragma unroll
    for (int hf = 0; hf < 2; hf++)
#pragma unroll
        for (int i = 0; i < 5; i++) ctxa[hf][i] = (floatx4)(0.f);

#pragma unroll
    for (int sub = 0; sub < 2; sub++) {
        int tb = b * SEQ + s * 256 + sub * 128;
        int arow = tb + w * 16 + ml;
        short8 af0 = *(const short8*)&Kbf[(size_t)arow * DIMX + h * DHE + q * 8];
        short8 af1 = *(const short8*)&Kbf[(size_t)arow * DIMX + h * DHE + 32 + q * 8];
        float ssr[4];
#pragma unroll
        for (int r = 0; r < 4; r++) ssr[r] = SS[h * PSEQ + tb + w * 16 + q * 4 + r];
#pragma unroll
        for (int hf = 0; hf < 2; hf++) {
            // --- XP phase for m = hf*144 .. hf*144+143 ---
#pragma unroll
            for (int cl = 0; cl < 9; cl++) {
                int c = hf * 9 + cl;
                floatx4 xp = (floatx4)(0.f);
                short8 b0 = *(const short8*)&Pbf[(c * 16 + ml) * DHE + q * 8];
                short8 b1 = *(const short8*)&Pbf[(c * 16 + ml) * DHE + 32 + q * 8];
                xp = __builtin_amdgcn_mfma_f32_16x16x32_bf16(af0, b0, xp, 0, 0, 0);
                xp = __builtin_amdgcn_mfma_f32_16x16x32_bf16(af1, b1, xp, 0, 0, 0);
                int m = c * 16 + ml;
                bool val = m < NB;
                float kpv[4];
#pragma unroll
                for (int r = 0; r < 4; r++)
                    kpv[r] = val ? RATIO_F * (__expf(xp[r] * DN_F - ssr[r] * 0.0625f - mx) + EPS_F)
                                 : 0.f;
                ushort4 pk;
                pk.x = f2bf(kpv[0]); pk.y = f2bf(kpv[1]);
                pk.z = f2bf(kpv[2]); pk.w = f2bf(kpv[3]);
                *(ushort4*)&kpT[(cl * 16 + ml) * KPT_LD + w * 16 + q * 4] = pk;
                float s4 = kpv[0] + kpv[1] + kpv[2] + kpv[3];
                s4 += __shfl_xor(s4, 16);
                s4 += __shfl_xor(s4, 32);
                if (q == 0) atomicAdd(&ksum_l[m], s4);
            }
            __syncthreads();
            // --- CTX phase: 36 tiles (9 mt x 4 dt) over 8 waves ---
#pragma unroll
            for (int sk = 0; sk < 4; sk++) {
#pragma unroll
                for (int i = 0; i < 5; i++) {
                    if (i < 4 || w < 4) {
                        int tt = w + i * 8;
                        int mtl = tt >> 2, dt = tt & 3;
                        short8 a = *(const short8*)&kpT[(mtl * 16 + ml) * KPT_LD + sk * 32 + q * 8];
                        short8 bv = *(const short8*)&Vt[((size_t)bh * DHE + dt * 16 + ml) * SEQ +
                                                        s * 256 + sub * 128 + sk * 32 + q * 8];
                        ctxa[hf][i] = __builtin_amdgcn_mfma_f32_16x16x32_bf16(a, bv, ctxa[hf][i], 0, 0, 0);
                    }
                }
            }
            __syncthreads();
        }
    }
    // --- coalesced output: stage each half through LDS, stream float4 ---
    float* stg = (float*)kpT;   // [144][68] floats = 39168 B
    float* cp = CTXP + ((size_t)bh * NSTRIP + s) * (MP * DHE);
#pragma unroll
    for (int hf = 0; hf < 2; hf++) {
        __syncthreads();
#pragma unroll
        for (int i = 0; i < 5; i++) {
            if (i < 4 || w < 4) {
                int tt = w + i * 8;
                int mtl = tt >> 2, dt = tt & 3;
#pragma unroll
                for (int r = 0; r < 4; r++)
                    stg[(mtl * 16 + q * 4 + r) * 68 + dt * 16 + ml] = ctxa[hf][i][r];
            }
        }
        __syncthreads();
        float4* cp4 = (float4*)(cp + (size_t)hf * 144 * DHE);
        for (int e4 = tid; e4 < 2304; e4 += 512) {
            int row = e4 >> 4, col4 = e4 & 15;
            cp4[e4] = ((const float4*)stg)[row * 17 + col4];
        }
    }
    if (tid < MP) atomicAdd(&KSUM[bh * MP + tid], ksum_l[tid]);
}

// -------- reduce CTX partials over 32 strips; emit bf16 CTX^T [bh][64][296] --------
__global__ __launch_bounds__(256) void ctx_reduce_kernel(const float* __restrict__ CTXP,
                                                         ushort_t* __restrict__ CTXbf) {
    int i = blockIdx.x * 256 + threadIdx.x;  // 16*288*64
    if (i < 16 * MP * DHE) {
        int bh = i / (MP * DHE);
        int e = i - bh * (MP * DHE);
        float s = 0.f;
#pragma unroll
        for (int st = 0; st < NSTRIP; st++)
            s += CTXP[((size_t)bh * NSTRIP + st) * (MP * DHE) + e];
        int m = e >> 6, d = e & 63;
        CTXbf[((size_t)bh * DHE + d) * CTXT_LD + m] = f2bf(s);
    }
}

// ---------------- fused qp + rowmax + denom + O = dinv*(qp@CTX) via MFMA ----------------
// grid 2048 = 16 bh x 128 tiles of 64 tokens; 4 waves; 3 blocks/CU.
// ctxt staging is a LINEAR bf16 copy (transpose+convert hoisted into ctx_reduce).
__global__ __launch_bounds__(256, 3) void qo_kernel(const ushort_t* __restrict__ Qbf,
                                                    const ushort_t* __restrict__ Pbf,
                                                    const float* __restrict__ SS,
                                                    const ushort_t* __restrict__ CTXbf,
                                                    const float* __restrict__ KSUM,
                                                    ushort_t* __restrict__ Ob) {
    __shared__ ushort_t ctxt[DHE * CTXT_LD];   // CTX^T bf16 [d][m], 37888 B
    __shared__ ushort_t qpA[4][16][40];        // per-wave qp chunk (no barriers needed)
    __shared__ float ksl[MP];
    int tid = threadIdx.x;
    int w = tid >> 6, lane = tid & 63;
    int q = lane >> 4, ml = lane & 15;
    int bh = blockIdx.x >> 7, tile = blockIdx.x & 127;
    int b = bh >> 3, h = bh & 7;
    const short8* Cg8 = (const short8*)(CTXbf + (size_t)bh * (DHE * CTXT_LD));
    short8* ct8 = (short8*)ctxt;
    for (int e = tid; e < (DHE * CTXT_LD) / 8; e += 256)  // 2368 chunks of 16B
        ct8[e] = Cg8[e];
    ksl[tid] = KSUM[bh * MP + tid];
    if (tid < MP - 256) ksl[256 + tid] = KSUM[bh * MP + 256 + tid];
    __syncthreads();
    int nl = tile * 64 + w * 16;
    int arow = b * SEQ + nl + ml;
    short8 af0 = *(const short8*)&Qbf[(size_t)arow * DIMX + h * DHE + q * 8];
    short8 af1 = *(const short8*)&Qbf[(size_t)arow * DIMX + h * DHE + 32 + q * 8];
    floatx4 xp[MT];
#pragma unroll
    for (int c = 0; c < MT; c++) {
        xp[c] = (floatx4)(0.f);
        short8 b0 = *(const short8*)&Pbf[(c * 16 + ml) * DHE + q * 8];
        short8 b1 = *(const short8*)&Pbf[(c * 16 + ml) * DHE + 32 + q * 8];
        xp[c] = __builtin_amdgcn_mfma_f32_16x16x32_bf16(af0, b0, xp[c], 0, 0, 0);
        xp[c] = __builtin_amdgcn_mfma_f32_16x16x32_bf16(af1, b1, xp[c], 0, 0, 0);
    }
    float ssr[4], rm[4], dp[4], dinv[4];
#pragma unroll
    for (int r = 0; r < 4; r++) {
        ssr[r] = SS[h * PSEQ + b * SEQ + nl + q * 4 + r];
        rm[r] = -3.0e38f;
        dp[r] = 0.f;
    }
#pragma unroll
    for (int c = 0; c < MT; c++) {
        int m = c * 16 + ml;
        bool val = m < NB;
#pragma unroll
        for (int r = 0; r < 4; r++) {
            float tv = xp[c][r] * DN_F;
            xp[c][r] = tv;
            if (val) rm[r] = fmaxf(rm[r], tv);
        }
    }
#pragma unroll
    for (int r = 0; r < 4; r++) {
        rm[r] = fmaxf(rm[r], __shfl_xor(rm[r], 1));
        rm[r] = fmaxf(rm[r], __shfl_xor(rm[r], 2));
        rm[r] = fmaxf(rm[r], __shfl_xor(rm[r], 4));
        rm[r] = fmaxf(rm[r], __shfl_xor(rm[r], 8));
    }
#pragma unroll
    for (int c = 0; c < MT; c++) {
        int m = c * 16 + ml;
        bool val = m < NB;
        float km = ksl[m];
#pragma unroll
        for (int r = 0; r < 4; r++) {
            float v = val ? RATIO_F * (__expf(xp[c][r] - ssr[r] * 0.0625f - rm[r]) + EPS_F) : 0.f;
            xp[c][r] = v;
            dp[r] += v * km;
        }
    }
#pragma unroll
    for (int r = 0; r < 4; r++) {
        dp[r] += __shfl_xor(dp[r], 1);
        dp[r] += __shfl_xor(dp[r], 2);
        dp[r] += __shfl_xor(dp[r], 4);
        dp[r] += __shfl_xor(dp[r], 8);
        dinv[r] = 1.0f / dp[r];
    }
    floatx4 oacc[4];
#pragma unroll
    for (int dt = 0; dt < 4; dt++) oacc[dt] = (floatx4)(0.f);
#pragma unroll
    for (int ks = 0; ks < 9; ks++) {
#pragma unroll
        for (int cc = 0; cc < 2; cc++) {
            int c = 2 * ks + cc;
#pragma unroll
            for (int r = 0; r < 4; r++)
                qpA[w][q * 4 + r][cc * 16 + ml] = f2bf(xp[c][r]);
        }
        // per-wave LDS RAW: DS ops are in-order within a wave; no block barrier needed
        short8 a = *(const short8*)&qpA[w][ml][q * 8];
#pragma unroll
        for (int dt = 0; dt < 4; dt++) {
            short8 bv = *(const short8*)&ctxt[(dt * 16 + ml) * CTXT_LD + ks * 32 + q * 8];
            oacc[dt] = __builtin_amdgcn_mfma_f32_16x16x32_bf16(a, bv, oacc[dt], 0, 0, 0);
        }
    }
#pragma unroll
    for (int dt = 0; dt < 4; dt++)
#pragma unroll
        for (int r = 0; r < 4; r++)
            Ob[(size_t)(b * SEQ + nl + q * 4 + r) * DIMX + h * DHE + dt * 16 + ml] =
                f2bf(oacc[dt][r] * dinv[r]);
}

extern "C" void kernel_launch(void* const* d_in, const int* in_sizes, int n_in,
                              void* d_out, int out_size, void* d_ws, size_t ws_size,
                              hipStream_t stream) {
    (void)in_sizes; (void)n_in; (void)out_size; (void)ws_size;
    const float* src  = (const float*)d_in[0];
    const float* proj = (const float*)d_in[1];
    const float* ln1g = (const float*)d_in[2];
    const float* ln1b = (const float*)d_in[3];
    const float* Wq   = (const float*)d_in[4];
    const float* Wk   = (const float*)d_in[5];
    const float* Wv   = (const float*)d_in[6];
    const float* Wo   = (const float*)d_in[7];
    const float* bo   = (const float*)d_in[8];
    const float* ln2g = (const float*)d_in[9];
    const float* ln2b = (const float*)d_in[10];
    const float* W1   = (const float*)d_in[11];
    const float* b1   = (const float*)d_in[12];
    const float* W2   = (const float*)d_in[13];
    const float* b2   = (const float*)d_in[14];
    const float* fcw  = (const float*)d_in[15];
    const float* fcb  = (const float*)d_in[16];
    float* out = (float*)d_out;

    // ---- workspace layout (~155 MiB of 162 safe) ----
    const size_t TD   = (size_t)NTOK * DIMX;
    const size_t PD   = (size_t)PSEQ * DIMX;
    float*    X    = (float*)d_ws;                      // 64 MiB residual fp32
    ushort_t* Hs   = (ushort_t*)(X + TD);               // 16 MiB LN out bf16 (pair)
    ushort_t* KQbf = Hs + PD;                           // 16 MiB K bf16, then Q bf16
    ushort_t* Vt   = KQbf + PD;                         // 16 MiB V^T per-head bf16
    float*    CTXP = (float*)(Vt + PD);                 // 36 MiB ctx partials (32 strips)
    ushort_t* Obuf = (ushort_t*)CTXP;                   // 16 MiB attn-out bf16, aliases CTXP
    ushort_t* CTXbf = (ushort_t*)(CTXP + (size_t)16 * NSTRIP * MP * DHE);  // 592 KiB bf16 CTX^T
    float*    KSUM = (float*)(CTXbf + (size_t)16 * DHE * CTXT_LD);  // 16x288
    unsigned int* KMAX = (unsigned int*)(KSUM + 16 * MP);
    float*    SS   = (float*)(KMAX + 4);                // [8][PSEQ]
    ushort_t* Pbf  = (ushort_t*)(SS + (size_t)NHEADS * PSEQ);  // [288][64] bf16
    ushort_t* Wtb  = Pbf + MP * DHE;                    // 6 MiB weights bf16
    ushort_t* Wqt = Wtb;
    ushort_t* Wkt = Wqt + DIMX * DIMX;
    ushort_t* Wvt = Wkt + DIMX * DIMX;
    ushort_t* Wot = Wvt + DIMX * DIMX;
    ushort_t* W1t = Wot + DIMX * DIMX;         // [FFD, DIMX]
    ushort_t* W2t = W1t + (size_t)DIMX * FFD;  // [DIMX, FFD]
    ushort_t* Hid = KQbf;  // FF hidden 64 MiB: aliases KQbf+Vt+CTXP head (all dead in FF)

    hipMemcpyAsync(X, src, sizeof(float) * TD, hipMemcpyDeviceToDevice, stream);

    dim3 gP(PSEQ / 128, DIMX / 128);   // (128,4)
    dim3 gF1(PSEQ / 128, FFD / 128);   // (128,16)
    const int lnGrid = PSEQ / 4;       // 4096
    for (int L = 0; L < NLAYER; L++) {
        const float* pj = proj + (size_t)L * NB * DHE;
        wconv4_kernel<<<dim3(16, 16, 4), 256, 0, stream>>>(
            Wq + (size_t)L * DIMX * DIMX, Wk + (size_t)L * DIMX * DIMX,
            Wv + (size_t)L * DIMX * DIMX, Wo + (size_t)L * DIMX * DIMX, Wqt);
        wconv_kernel<<<dim3(64, 16), 256, 0, stream>>>(W1 + (size_t)L * DIMX * FFD, W1t, DIMX, FFD);
        wconv_kernel<<<dim3(16, 64), 256, 0, stream>>>(W2 + (size_t)L * FFD * DIMX, W2t, FFD, DIMX);
        projconv_kernel<<<(MP * DHE + 255) / 256, 256, 0, stream>>>(pj, Pbf);
        zero_kernel<<<1, 256, 0, stream>>>((float*)KMAX, 1);
        // --- phase A: global key-feature max over both pairs ---
        for (int p = 0; p < 2; p++) {
            const float* Xp = X + (size_t)p * PD;
            ln_bf16_kernel<<<lnGrid, 256, 0, stream>>>(Xp, ln1g + L * DIMX, ln1b + L * DIMX, Hs);
            gemm_mfma<5><<<gP, 256, 0, stream>>>(Hs, Wkt, nullptr, nullptr, KQbf, SS, PSEQ, DIMX, DIMX);
            kmax_kernel<<<512, 512, 0, stream>>>(KQbf, Pbf, KMAX);
        }
        // --- phase B: attention + FF per pair (p=1 first: Hs/KQbf/SS still hold pair-1) ---
        for (int pp = 0; pp < 2; pp++) {
            int p = 1 - pp;
            float* Xp = X + (size_t)p * PD;
            if (p == 0) {
                ln_bf16_kernel<<<lnGrid, 256, 0, stream>>>(Xp, ln1g + L * DIMX, ln1b + L * DIMX, Hs);
                gemm_mfma<5><<<gP, 256, 0, stream>>>(Hs, Wkt, nullptr, nullptr, KQbf, SS, PSEQ, DIMX, DIMX);
            }
            gemm_mfma<4><<<gP, 256, 0, stream>>>(Hs, Wvt, nullptr, nullptr, Vt, nullptr, PSEQ, DIMX, DIMX);
            zero_kernel<<<(16 * MP + 255) / 256, 256, 0, stream>>>(KSUM, 16 * MP);
            kctx_kernel<<<16 * NSTRIP, 512, 0, stream>>>(KQbf, Pbf, SS, KMAX, Vt, CTXP, KSUM);
            ctx_reduce_kernel<<<(16 * MP * DHE + 255) / 256, 256, 0, stream>>>(CTXP, CTXbf);
            gemm_mfma<5><<<gP, 256, 0, stream>>>(Hs, Wqt, nullptr, nullptr, KQbf, SS, PSEQ, DIMX, DIMX);
            qo_kernel<<<2048, 256, 0, stream>>>(KQbf, Pbf, SS, CTXbf, KSUM, Obuf);
            gemm_mfma<1><<<gP, 256, 0, stream>>>(Obuf, Wot, bo + L * DIMX, Xp, nullptr, nullptr, PSEQ, DIMX, DIMX);
            // --- FF ---
            ln_bf16_kernel<<<lnGrid, 256, 0, stream>>>(Xp, ln2g + L * DIMX, ln2b + L * DIMX, Hs);
            gemm_mfma<2><<<gF1, 256, 0, stream>>>(Hs, W1t, b1 + L * FFD, nullptr, Hid, nullptr, PSEQ, FFD, DIMX);
            gemm_mfma<1><<<gP, 256, 0, stream>>>(Hid, W2t, b2 + L * DIMX, Xp, nullptr, nullptr, PSEQ, DIMX, FFD);
        }
    }
    gemm_kernel<0, 0><<<dim3(NTOK / 128, 1), 256, 0, stream>>>(X, fcw, fcb, out, NTOK, OUTD, DIMX);
}

// Round 6
// 4986.214 us; speedup vs baseline: 8.7854x; 1.1007x over previous
//
#include <hip/hip_runtime.h>
#include <math.h>

#define DIMX 512
#define NHEADS 8
#define DHE 64
#define NB 266
#define MP 288          // NB padded to 18 MFMA col-tiles
#define MT 18           // MP/16
#define KPT_LD 136      // kpT row stride (128+8) to break banks
#define CTXT_LD 296     // ctxt row stride (288+8)
#define NSTRIP 32       // strips per (b,h) in kctx
#define FFD 2048
#define OUTD 32
#define SEQ 8192
#define NTOK 32768
#define NLAYER 6
#define PSEQ 16384      // tokens per batch-pair

#define DN_F 0.35355339059327373f
#define RATIO_F 0.06131393f
#define EPS_F 1e-4f

typedef unsigned short ushort_t;
typedef __attribute__((ext_vector_type(8))) short short8;
typedef __attribute__((ext_vector_type(4))) float floatx4;

// gelu(x) = 0.5x(1+tanh(z)) = x * sigmoid(2z), z = 0.79788456(x + 0.044715 x^3)
__device__ __forceinline__ float gelu_f(float x) {
    float s = x * x;
    float t = fmaf(0.044715f, s, 1.0f);
    float u = -1.5957691216057308f * x * t;     // -2z
    float e = __expf(u);
    return x * __builtin_amdgcn_rcpf(1.0f + e); // large +x -> e=0 -> x; large -x -> rcp(inf)=0
}

__device__ __forceinline__ ushort_t f2bf(float f) {
    unsigned int u = __float_as_uint(f);
    unsigned int r = (u + 0x7fffu + ((u >> 16) & 1u)) >> 16;
    return (ushort_t)r;
}

__device__ __forceinline__ float bf2f(ushort_t u) {
    return __uint_as_float(((unsigned int)u) << 16);
}

__device__ __forceinline__ unsigned int fkey(float f) {
    unsigned int u = __float_as_uint(f);
    return (u & 0x80000000u) ? ~u : (u | 0x80000000u);
}
__device__ __forceinline__ float funkey(unsigned int k) {
    unsigned int u = (k & 0x80000000u) ? (k & 0x7fffffffu) : ~k;
    return __uint_as_float(u);
}

// async global->LDS 16B per lane; LDS dest = wave-uniform base + lane*16
__device__ __forceinline__ void gl_lds16(const void* g, void* l) {
    __builtin_amdgcn_global_load_lds(
        (const __attribute__((address_space(1))) unsigned int*)g,
        (__attribute__((address_space(3))) unsigned int*)l, 16, 0, 0);
}

__global__ __launch_bounds__(256) void zero_kernel(float* __restrict__ p, int n) {
    int i = blockIdx.x * 256 + threadIdx.x;
    if (i < n) p[i] = 0.f;
}

// ---------------- LayerNorm -> bf16 out: one wave per 512-float row ----------------
__global__ __launch_bounds__(256) void ln_bf16_kernel(const float* __restrict__ x,
                                                      const float* __restrict__ g,
                                                      const float* __restrict__ b,
                                                      ushort_t* __restrict__ out) {
    int row = blockIdx.x * 4 + (threadIdx.x >> 6);
    int lane = threadIdx.x & 63;
    const float4* xr = (const float4*)(x + (size_t)row * DIMX);
    float4 v0 = xr[lane];
    float4 v1 = xr[lane + 64];
    float sum = v0.x + v0.y + v0.z + v0.w + v1.x + v1.y + v1.z + v1.w;
#pragma unroll
    for (int off = 32; off; off >>= 1) sum += __shfl_xor(sum, off);
    float mu = sum * (1.0f / 512.0f);
    float var = (v0.x - mu) * (v0.x - mu) + (v0.y - mu) * (v0.y - mu) +
                (v0.z - mu) * (v0.z - mu) + (v0.w - mu) * (v0.w - mu) +
                (v1.x - mu) * (v1.x - mu) + (v1.y - mu) * (v1.y - mu) +
                (v1.z - mu) * (v1.z - mu) + (v1.w - mu) * (v1.w - mu);
#pragma unroll
    for (int off = 32; off; off >>= 1) var += __shfl_xor(var, off);
    float rstd = rsqrtf(var * (1.0f / 512.0f) + 1e-5f);
    const float4* g4 = (const float4*)g;
    const float4* b4 = (const float4*)b;
    ushort_t* orow = out + (size_t)row * DIMX;
    float4 gg = g4[lane], bb = b4[lane];
    ushort4 o;
    o.x = f2bf((v0.x - mu) * rstd * gg.x + bb.x);
    o.y = f2bf((v0.y - mu) * rstd * gg.y + bb.y);
    o.z = f2bf((v0.z - mu) * rstd * gg.z + bb.z);
    o.w = f2bf((v0.w - mu) * rstd * gg.w + bb.w);
    *(ushort4*)(orow + lane * 4) = o;
    gg = g4[lane + 64]; bb = b4[lane + 64];
    o.x = f2bf((v1.x - mu) * rstd * gg.x + bb.x);
    o.y = f2bf((v1.y - mu) * rstd * gg.y + bb.y);
    o.z = f2bf((v1.z - mu) * rstd * gg.z + bb.z);
    o.w = f2bf((v1.w - mu) * rstd * gg.w + bb.w);
    *(ushort4*)(orow + 256 + lane * 4) = o;
}

// ---------------- weight transpose-convert: W[K,N] fp32 -> Wt[N,K] bf16 ----------------
__global__ __launch_bounds__(256) void wconv_kernel(const float* __restrict__ W,
                                                    ushort_t* __restrict__ Wt,
                                                    int K, int N) {
    __shared__ float tile[32][33];
    int bx = blockIdx.x * 32;  // n
    int by = blockIdx.y * 32;  // k
    int tx = threadIdx.x & 31, ty = threadIdx.x >> 5;
#pragma unroll
    for (int r = 0; r < 4; r++)
        tile[ty + r * 8][tx] = W[(size_t)(by + ty + r * 8) * N + bx + tx];
    __syncthreads();
#pragma unroll
    for (int r = 0; r < 4; r++)
        Wt[(size_t)(bx + ty + r * 8) * K + by + tx] = f2bf(tile[tx][ty + r * 8]);
}

// 4 square 512x512 weights in one launch (grid.z selects)
__global__ __launch_bounds__(256) void wconv4_kernel(const float* __restrict__ W0,
                                                     const float* __restrict__ W1,
                                                     const float* __restrict__ W2,
                                                     const float* __restrict__ W3,
                                                     ushort_t* __restrict__ Wt) {
    __shared__ float tile[32][33];
    const float* Ws[4] = {W0, W1, W2, W3};
    const float* W = Ws[blockIdx.z];
    ushort_t* Wd = Wt + (size_t)blockIdx.z * DIMX * DIMX;
    int bx = blockIdx.x * 32;
    int by = blockIdx.y * 32;
    int tx = threadIdx.x & 31, ty = threadIdx.x >> 5;
#pragma unroll
    for (int r = 0; r < 4; r++)
        tile[ty + r * 8][tx] = W[(size_t)(by + ty + r * 8) * DIMX + bx + tx];
    __syncthreads();
#pragma unroll
    for (int r = 0; r < 4; r++)
        Wd[(size_t)(bx + ty + r * 8) * DIMX + by + tx] = f2bf(tile[tx][ty + r * 8]);
}

// ---------------- proj fp32 [266][64] -> bf16 [288][64] (pad rows zero) ----------------
__global__ __launch_bounds__(256) void projconv_kernel(const float* __restrict__ proj,
                                                       ushort_t* __restrict__ Pbf) {
    int i = blockIdx.x * 256 + threadIdx.x;
    if (i < MP * DHE) {
        int m = i >> 6;
        Pbf[i] = (m < NB) ? f2bf(proj[i]) : (ushort_t)0;
    }
}

// ---------------- bf16 MFMA GEMM: 128x128 tile, 16x16x32, 2-phase double-buffered ----------
// A[M,K] bf16 row-major; Bt[N,K] bf16 row-major.
// XCD-aware swizzle: per-XCD contiguous m-panel (A fits 4MB L2); requires nwg % 8 == 0.
// EPI 1: C += A@B + bias (fp32). EPI 2: Cb = bf16(gelu(A@B+bias)).
// EPI 4: transposed per-head bf16: Vt[(b*8+h)*64+d][8192].
// EPI 5: Cb = bf16(A@B) and SS[head][row] = sum over head cols of v^2.
template <int EPI>
__global__ __launch_bounds__(256) void gemm_mfma(const ushort_t* __restrict__ A,
                                                 const ushort_t* __restrict__ Bt,
                                                 const float* __restrict__ bias,
                                                 float* __restrict__ C,
                                                 ushort_t* __restrict__ Cb,
                                                 float* __restrict__ SS,
                                                 int M, int N, int K) {
    __shared__ ushort_t As[2][128 * 32];
    __shared__ ushort_t Bs[2][128 * 32];
    int t = threadIdx.x;
    int wave = t >> 6, lane = t & 63;
    int wm = wave >> 1, wn = wave & 1;
    // bijective XCD swizzle; decode n-fastest so each XCD owns a contiguous m-panel
    int gy = gridDim.y;
    int orig = blockIdx.x + blockIdx.y * gridDim.x;
    int cpx = (gridDim.x * gy) >> 3;
    int swz = (orig & 7) * cpx + (orig >> 3);
    int m0 = (swz / gy) * 128, n0 = (swz - (swz / gy) * gy) * 128;
    int q = lane >> 4, ml = lane & 15;

    floatx4 acc[4][4];
#pragma unroll
    for (int i = 0; i < 4; i++)
#pragma unroll
        for (int j = 0; j < 4; j++) acc[i][j] = (floatx4)(0.f);

    int srow = (lane >> 2);
    int scol = (lane & 3) * 8;
    const ushort_t* Ag = A + (size_t)(m0 + wave * 32 + srow) * K + scol;
    const ushort_t* Bg = Bt + (size_t)(n0 + wave * 32 + srow) * K + scol;
    ushort_t* AsW[2] = {&As[0][(wave * 32) * 32], &As[1][(wave * 32) * 32]};
    ushort_t* BsW[2] = {&Bs[0][(wave * 32) * 32], &Bs[1][(wave * 32) * 32]};

    // prologue: stage tile 0 into buffer 0
    gl_lds16(Ag, AsW[0]);
    gl_lds16(Ag + (size_t)16 * K, AsW[0] + 16 * 32);
    gl_lds16(Bg, BsW[0]);
    gl_lds16(Bg + (size_t)16 * K, BsW[0] + 16 * 32);
    __syncthreads();

    int cur = 0;
    for (int k0 = 32; k0 < K; k0 += 32) {
        int nxt = cur ^ 1;
        // issue next-tile staging first: HBM latency hides under ds_read+MFMA below
        gl_lds16(Ag + k0, AsW[nxt]);
        gl_lds16(Ag + k0 + (size_t)16 * K, AsW[nxt] + 16 * 32);
        gl_lds16(Bg + k0, BsW[nxt]);
        gl_lds16(Bg + k0 + (size_t)16 * K, BsW[nxt] + 16 * 32);
        // compute current buffer
        const ushort_t* Ac = &As[cur][0];
        const ushort_t* Bc = &Bs[cur][0];
        short8 a[4], b[4];
#pragma unroll
        for (int i = 0; i < 4; i++)
            a[i] = *(const short8*)&Ac[(wm * 64 + i * 16 + ml) * 32 + q * 8];
#pragma unroll
        for (int j = 0; j < 4; j++)
            b[j] = *(const short8*)&Bc[(wn * 64 + j * 16 + ml) * 32 + q * 8];
#pragma unroll
        for (int i = 0; i < 4; i++)
#pragma unroll
            for (int j = 0; j < 4; j++)
                acc[i][j] = __builtin_amdgcn_mfma_f32_16x16x32_bf16(a[i], b[j], acc[i][j], 0, 0, 0);
        // one barrier per step: drains own vmcnt (next staged) + lgkm (reads of cur done)
        __syncthreads();
        cur = nxt;
    }
    {   // final tile: no staging, no trailing barrier (epilogue touches only regs/global)
        const ushort_t* Ac = &As[cur][0];
        const ushort_t* Bc = &Bs[cur][0];
        short8 a[4], b[4];
#pragma unroll
        for (int i = 0; i < 4; i++)
            a[i] = *(const short8*)&Ac[(wm * 64 + i * 16 + ml) * 32 + q * 8];
#pragma unroll
        for (int j = 0; j < 4; j++)
            b[j] = *(const short8*)&Bc[(wn * 64 + j * 16 + ml) * 32 + q * 8];
#pragma unroll
        for (int i = 0; i < 4; i++)
#pragma unroll
            for (int j = 0; j < 4; j++)
                acc[i][j] = __builtin_amdgcn_mfma_f32_16x16x32_bf16(a[i], b[j], acc[i][j], 0, 0, 0);
    }

    if (EPI == 4) {
#pragma unroll
        for (int i = 0; i < 4; i++) {
            size_t r0 = (size_t)m0 + wm * 64 + i * 16 + q * 4;
            int bb = (int)(r0 >> 13);
            int nl = (int)(r0 & (SEQ - 1));
#pragma unroll
            for (int j = 0; j < 4; j++) {
                int col = n0 + wn * 64 + j * 16 + ml;
                int hh = col >> 6, dd = col & 63;
                ushort4 pk;
                pk.x = f2bf(acc[i][j][0]); pk.y = f2bf(acc[i][j][1]);
                pk.z = f2bf(acc[i][j][2]); pk.w = f2bf(acc[i][j][3]);
                *(ushort4*)&Cb[(((size_t)bb * 8 + hh) * DHE + dd) * SEQ + nl] = pk;
            }
        }
    } else if (EPI == 5) {
        int hh = (n0 >> 6) + wn;  // each wave's 64 cols = one head
#pragma unroll
        for (int i = 0; i < 4; i++) {
#pragma unroll
            for (int r = 0; r < 4; r++) {
                size_t row = (size_t)m0 + wm * 64 + i * 16 + q * 4 + r;
                float sq = 0.f;
#pragma unroll
                for (int j = 0; j < 4; j++) {
                    int col = n0 + wn * 64 + j * 16 + ml;
                    float v = acc[i][j][r];
                    sq += v * v;
                    Cb[row * N + col] = f2bf(v);
                }
                sq += __shfl_xor(sq, 1);
                sq += __shfl_xor(sq, 2);
                sq += __shfl_xor(sq, 4);
                sq += __shfl_xor(sq, 8);
                if (ml == 0) SS[(size_t)hh * PSEQ + row] = sq;
            }
        }
    } else {
#pragma unroll
        for (int i = 0; i < 4; i++) {
#pragma unroll
            for (int r = 0; r < 4; r++) {
                size_t row = (size_t)m0 + wm * 64 + i * 16 + q * 4 + r;
#pragma unroll
                for (int j = 0; j < 4; j++) {
                    int col = n0 + wn * 64 + j * 16 + ml;
                    float v = acc[i][j][r];
                    if (EPI == 1) {
                        C[row * N + col] += v + bias[col];
                    } else if (EPI == 2) {
                        Cb[row * N + col] = f2bf(gelu_f(v + bias[col]));
                    }
                }
            }
        }
    }
}

// ---------------- fp32 VALU GEMM (final fc, N=32) ----------------
template <int DOACC, int DOGELU>
__global__ __launch_bounds__(256) void gemm_kernel(const float* __restrict__ A,
                                                   const float* __restrict__ B,
                                                   const float* __restrict__ bias,
                                                   float* __restrict__ C,
                                                   int M, int N, int K) {
    __shared__ float As[16][132];
    __shared__ float Bs[16][132];
    int t = threadIdx.x;
    int tx = t & 15, ty = t >> 4;
    int m0 = blockIdx.x * 128;
    int n0 = blockIdx.y * 128;
    float c[8][8];
#pragma unroll
    for (int i = 0; i < 8; i++)
#pragma unroll
        for (int j = 0; j < 8; j++) c[i][j] = 0.f;
    int am = t >> 1;
    int ak = (t & 1) * 8;
    const float* Aptr = A + (size_t)(m0 + am) * K + ak;
    int bn = (t & 15) * 8;
    int bk = t >> 4;
    bool bvalid = (n0 + bn) < N;
    const float* Bptr = B + (size_t)bk * N + n0 + bn;
    for (int k0 = 0; k0 < K; k0 += 16) {
        float4 a0 = *(const float4*)(Aptr + k0);
        float4 a1 = *(const float4*)(Aptr + k0 + 4);
        As[ak + 0][am] = a0.x; As[ak + 1][am] = a0.y;
        As[ak + 2][am] = a0.z; As[ak + 3][am] = a0.w;
        As[ak + 4][am] = a1.x; As[ak + 5][am] = a1.y;
        As[ak + 6][am] = a1.z; As[ak + 7][am] = a1.w;
        float4 b0 = make_float4(0.f, 0.f, 0.f, 0.f);
        float4 b1v = make_float4(0.f, 0.f, 0.f, 0.f);
        if (bvalid) {
            const float* bp = Bptr + (size_t)k0 * N;
            b0 = *(const float4*)bp;
            b1v = *(const float4*)(bp + 4);
        }
        *(float4*)&Bs[bk][bn] = b0;
        *(float4*)&Bs[bk][bn + 4] = b1v;
        __syncthreads();
#pragma unroll
        for (int kk = 0; kk < 16; kk++) {
            float4 av0 = *(const float4*)&As[kk][ty * 4];
            float4 av1 = *(const float4*)&As[kk][64 + ty * 4];
            float4 bv0 = *(const float4*)&Bs[kk][tx * 4];
            float4 bv1 = *(const float4*)&Bs[kk][64 + tx * 4];
            float a_[8] = {av0.x, av0.y, av0.z, av0.w, av1.x, av1.y, av1.z, av1.w};
            float b_[8] = {bv0.x, bv0.y, bv0.z, bv0.w, bv1.x, bv1.y, bv1.z, bv1.w};
#pragma unroll
            for (int i = 0; i < 8; i++)
#pragma unroll
                for (int j = 0; j < 8; j++) c[i][j] += a_[i] * b_[j];
        }
        __syncthreads();
    }
#pragma unroll
    for (int ih = 0; ih < 2; ih++)
#pragma unroll
        for (int il = 0; il < 4; il++) {
            size_t row = (size_t)m0 + ih * 64 + ty * 4 + il;
#pragma unroll
            for (int jh = 0; jh < 2; jh++) {
                int colbase = n0 + jh * 64 + tx * 4;
                if (colbase < N) {
                    float* cp = C + row * N + colbase;
#pragma unroll
                    for (int jl = 0; jl < 4; jl++) {
                        float v = c[ih * 4 + il][jh * 4 + jl];
                        if (bias) v += bias[colbase + jl];
                        if (DOGELU) v = gelu_f(v);
                        if (DOACC) v += cp[jl];
                        cp[jl] = v;
                    }
                }
            }
        }
}

// ---------------- global key-feature max via MFMA: grid 512 = 8 heads x 64 tiles ------------
__global__ __launch_bounds__(512) void kmax_kernel(const ushort_t* __restrict__ Kbf,
                                                   const ushort_t* __restrict__ Pbf,
                                                   unsigned int* __restrict__ kmaxkey) {
    __shared__ float wred[8];
    int tid = threadIdx.x;
    int w = tid >> 6, lane = tid & 63;
    int q = lane >> 4, ml = lane & 15;
    int h = blockIdx.x >> 6, tile = blockIdx.x & 63;
    float lm = -3.0e38f;
#pragma unroll
    for (int sub = 0; sub < 2; sub++) {
        int arow = tile * 256 + sub * 128 + w * 16 + ml;
        short8 af0 = *(const short8*)&Kbf[(size_t)arow * DIMX + h * DHE + q * 8];
        short8 af1 = *(const short8*)&Kbf[(size_t)arow * DIMX + h * DHE + 32 + q * 8];
#pragma unroll
        for (int c = 0; c < 17; c++) {
            floatx4 xp = (floatx4)(0.f);
            short8 b0 = *(const short8*)&Pbf[(c * 16 + ml) * DHE + q * 8];
            short8 b1 = *(const short8*)&Pbf[(c * 16 + ml) * DHE + 32 + q * 8];
            xp = __builtin_amdgcn_mfma_f32_16x16x32_bf16(af0, b0, xp, 0, 0, 0);
            xp = __builtin_amdgcn_mfma_f32_16x16x32_bf16(af1, b1, xp, 0, 0, 0);
            if (c * 16 + ml < NB)
                lm = fmaxf(lm, fmaxf(fmaxf(xp[0], xp[1]), fmaxf(xp[2], xp[3])));
        }
    }
    lm *= DN_F;
#pragma unroll
    for (int off = 32; off; off >>= 1) lm = fmaxf(lm, __shfl_xor(lm, off));
    if (lane == 0) wred[w] = lm;
    __syncthreads();
    if (tid == 0) {
        float bm = wred[0];
#pragma unroll
        for (int ww = 1; ww < 8; ww++) bm = fmaxf(bm, wred[ww]);
        atomicMax(kmaxkey, fkey(bm));
    }
}

// ---------------- fused kp + CTX partial via MFMA (half-split kpT, 2 blocks/CU) ------------
__global__ __launch_bounds__(512, 4) void kctx_kernel(const ushort_t* __restrict__ Kbf,
                                                      const ushort_t* __restrict__ Pbf,
                                                      const float* __restrict__ SS,
                                                      const unsigned int* __restrict__ kmaxkey,
                                                      const ushort_t* __restrict__ Vt,
                                                      float* __restrict__ CTXP,
                                                      float* __restrict__ KSUM) {
    __shared__ ushort_t kpT[144 * KPT_LD];   // 39168 B; reused as float[144][68] for output
    __shared__ float ksum_l[MP];
    int tid = threadIdx.x;
    int w = tid >> 6, lane = tid & 63;
    int q = lane >> 4, ml = lane & 15;
    int bh = blockIdx.x >> 5, s = blockIdx.x & 31;
    int b = bh >> 3, h = bh & 7;
    float mx = funkey(*kmaxkey);
    if (tid < MP) ksum_l[tid] = 0.f;
    __syncthreads();
    floatx4 ctxa[2][5];
#pragma unroll
    for (int hf = 0; hf < 2; hf++)
#pragma unroll
        for (int i = 0; i < 5; i++) ctxa[hf][i] = (floatx4)(0.f);

#pragma unroll
    for (int sub = 0; sub < 2; sub++) {
        int tb = b * SEQ + s * 256 + sub * 128;
        int arow = tb + w * 16 + ml;
        short8 af0 = *(const short8*)&Kbf[(size_t)arow * DIMX + h * DHE + q * 8];
        short8 af1 = *(const short8*)&Kbf[(size_t)arow * DIMX + h * DHE + 32 + q * 8];
        float ssr[4];
#pragma unroll
        for (int r = 0; r < 4; r++) ssr[r] = SS[h * PSEQ + tb + w * 16 + q * 4 + r];
#pragma unroll
        for (int hf = 0; hf < 2; hf++) {
            // --- XP phase for m = hf*144 .. hf*144+143 ---
#pragma unroll
            for (int cl = 0; cl < 9; cl++) {
                int c = hf * 9 + cl;
                floatx4 xp = (floatx4)(0.f);
                short8 b0 = *(const short8*)&Pbf[(c * 16 + ml) * DHE + q * 8];
                short8 b1 = *(const short8*)&Pbf[(c * 16 + ml) * DHE + 32 + q * 8];
                xp = __builtin_amdgcn_mfma_f32_16x16x32_bf16(af0, b0, xp, 0, 0, 0);
                xp = __builtin_amdgcn_mfma_f32_16x16x32_bf16(af1, b1, xp, 0, 0, 0);
                int m = c * 16 + ml;
                bool val = m < NB;
                float kpv[4];
#pragma unroll
                for (int r = 0; r < 4; r++)
                    kpv[r] = val ? RATIO_F * (__expf(xp[r] * DN_F - ssr[r] * 0.0625f - mx) + EPS_F)
                                 : 0.f;
                ushort4 pk;
                pk.x = f2bf(kpv[0]); pk.y = f2bf(kpv[1]);
                pk.z = f2bf(kpv[2]); pk.w = f2bf(kpv[3]);
                *(ushort4*)&kpT[(cl * 16 + ml) * KPT_LD + w * 16 + q * 4] = pk;
                float s4 = kpv[0] + kpv[1] + kpv[2] + kpv[3];
                s4 += __shfl_xor(s4, 16);
                s4 += __shfl_xor(s4, 32);
                if (q == 0) atomicAdd(&ksum_l[m], s4);
            }
            __syncthreads();
            // --- CTX phase: 36 tiles (9 mt x 4 dt) over 8 waves ---
#pragma unroll
            for (int sk = 0; sk < 4; sk++) {
#pragma unroll
                for (int i = 0; i < 5; i++) {
                    if (i < 4 || w < 4) {
                        int tt = w + i * 8;
                        int mtl = tt >> 2, dt = tt & 3;
                        short8 a = *(const short8*)&kpT[(mtl * 16 + ml) * KPT_LD + sk * 32 + q * 8];
                        short8 bv = *(const short8*)&Vt[((size_t)bh * DHE + dt * 16 + ml) * SEQ +
                                                        s * 256 + sub * 128 + sk * 32 + q * 8];
                        ctxa[hf][i] = __builtin_amdgcn_mfma_f32_16x16x32_bf16(a, bv, ctxa[hf][i], 0, 0, 0);
                    }
                }
            }
            __syncthreads();
        }
    }
    // --- coalesced output: stage each half through LDS, stream float4 ---
    float* stg = (float*)kpT;   // [144][68] floats = 39168 B
    float* cp = CTXP + ((size_t)bh * NSTRIP + s) * (MP * DHE);
#pragma unroll
    for (int hf = 0; hf < 2; hf++) {
        __syncthreads();
#pragma unroll
        for (int i = 0; i < 5; i++) {
            if (i < 4 || w < 4) {
                int tt = w + i * 8;
                int mtl = tt >> 2, dt = tt & 3;
#pragma unroll
                for (int r = 0; r < 4; r++)
                    stg[(mtl * 16 + q * 4 + r) * 68 + dt * 16 + ml] = ctxa[hf][i][r];
            }
        }
        __syncthreads();
        float4* cp4 = (float4*)(cp + (size_t)hf * 144 * DHE);
        for (int e4 = tid; e4 < 2304; e4 += 512) {
            int row = e4 >> 4, col4 = e4 & 15;
            cp4[e4] = ((const float4*)stg)[row * 17 + col4];
        }
    }
    if (tid < MP) atomicAdd(&KSUM[bh * MP + tid], ksum_l[tid]);
}

// -------- reduce CTX partials over 32 strips; emit bf16 CTX^T [bh][64][296] --------
__global__ __launch_bounds__(256) void ctx_reduce_kernel(const float* __restrict__ CTXP,
                                                         ushort_t* __restrict__ CTXbf) {
    int i = blockIdx.x * 256 + threadIdx.x;  // 16*288*64
    if (i < 16 * MP * DHE) {
        int bh = i / (MP * DHE);
        int e = i - bh * (MP * DHE);
        float s = 0.f;
#pragma unroll
        for (int st = 0; st < NSTRIP; st++)
            s += CTXP[((size_t)bh * NSTRIP + st) * (MP * DHE) + e];
        int m = e >> 6, d = e & 63;
        CTXbf[((size_t)bh * DHE + d) * CTXT_LD + m] = f2bf(s);
    }
}

// ---------------- fused qp + rowmax + denom + O = dinv*(qp@CTX) via MFMA ----------------
__global__ __launch_bounds__(256, 3) void qo_kernel(const ushort_t* __restrict__ Qbf,
                                                    const ushort_t* __restrict__ Pbf,
                                                    const float* __restrict__ SS,
                                                    const ushort_t* __restrict__ CTXbf,
                                                    const float* __restrict__ KSUM,
                                                    ushort_t* __restrict__ Ob) {
    __shared__ ushort_t ctxt[DHE * CTXT_LD];   // CTX^T bf16 [d][m], 37888 B
    __shared__ ushort_t qpA[4][16][40];        // per-wave qp chunk (no barriers needed)
    __shared__ float ksl[MP];
    int tid = threadIdx.x;
    int w = tid >> 6, lane = tid & 63;
    int q = lane >> 4, ml = lane & 15;
    int bh = blockIdx.x >> 7, tile = blockIdx.x & 127;
    int b = bh >> 3, h = bh & 7;
    const short8* Cg8 = (const short8*)(CTXbf + (size_t)bh * (DHE * CTXT_LD));
    short8* ct8 = (short8*)ctxt;
    for (int e = tid; e < (DHE * CTXT_LD) / 8; e += 256)  // 2368 chunks of 16B
        ct8[e] = Cg8[e];
    ksl[tid] = KSUM[bh * MP + tid];
    if (tid < MP - 256) ksl[256 + tid] = KSUM[bh * MP + 256 + tid];
    __syncthreads();
    int nl = tile * 64 + w * 16;
    int arow = b * SEQ + nl + ml;
    short8 af0 = *(const short8*)&Qbf[(size_t)arow * DIMX + h * DHE + q * 8];
    short8 af1 = *(const short8*)&Qbf[(size_t)arow * DIMX + h * DHE + 32 + q * 8];
    floatx4 xp[MT];
#pragma unroll
    for (int c = 0; c < MT; c++) {
        xp[c] = (floatx4)(0.f);
        short8 b0 = *(const short8*)&Pbf[(c * 16 + ml) * DHE + q * 8];
        short8 b1 = *(const short8*)&Pbf[(c * 16 + ml) * DHE + 32 + q * 8];
        xp[c] = __builtin_amdgcn_mfma_f32_16x16x32_bf16(af0, b0, xp[c], 0, 0, 0);
        xp[c] = __builtin_amdgcn_mfma_f32_16x16x32_bf16(af1, b1, xp[c], 0, 0, 0);
    }
    float ssr[4], rm[4], dp[4], dinv[4];
#pragma unroll
    for (int r = 0; r < 4; r++) {
        ssr[r] = SS[h * PSEQ + b * SEQ + nl + q * 4 + r];
        rm[r] = -3.0e38f;
        dp[r] = 0.f;
    }
#pragma unroll
    for (int c = 0; c < MT; c++) {
        int m = c * 16 + ml;
        bool val = m < NB;
#pragma unroll
        for (int r = 0; r < 4; r++) {
            float tv = xp[c][r] * DN_F;
            xp[c][r] = tv;
            if (val) rm[r] = fmaxf(rm[r], tv);
        }
    }
#pragma unroll
    for (int r = 0; r < 4; r++) {
        rm[r] = fmaxf(rm[r], __shfl_xor(rm[r], 1));
        rm[r] = fmaxf(rm[r], __shfl_xor(rm[r], 2));
        rm[r] = fmaxf(rm[r], __shfl_xor(rm[r], 4));
        rm[r] = fmaxf(rm[r], __shfl_xor(rm[r], 8));
    }
#pragma unroll
    for (int c = 0; c < MT; c++) {
        int m = c * 16 + ml;
        bool val = m < NB;
        float km = ksl[m];
#pragma unroll
        for (int r = 0; r < 4; r++) {
            float v = val ? RATIO_F * (__expf(xp[c][r] - ssr[r] * 0.0625f - rm[r]) + EPS_F) : 0.f;
            xp[c][r] = v;
            dp[r] += v * km;
        }
    }
#pragma unroll
    for (int r = 0; r < 4; r++) {
        dp[r] += __shfl_xor(dp[r], 1);
        dp[r] += __shfl_xor(dp[r], 2);
        dp[r] += __shfl_xor(dp[r], 4);
        dp[r] += __shfl_xor(dp[r], 8);
        dinv[r] = 1.0f / dp[r];
    }
    floatx4 oacc[4];
#pragma unroll
    for (int dt = 0; dt < 4; dt++) oacc[dt] = (floatx4)(0.f);
#pragma unroll
    for (int ks = 0; ks < 9; ks++) {
#pragma unroll
        for (int cc = 0; cc < 2; cc++) {
            int c = 2 * ks + cc;
#pragma unroll
            for (int r = 0; r < 4; r++)
                qpA[w][q * 4 + r][cc * 16 + ml] = f2bf(xp[c][r]);
        }
        // per-wave LDS RAW: DS ops are in-order within a wave; no block barrier needed
        short8 a = *(const short8*)&qpA[w][ml][q * 8];
#pragma unroll
        for (int dt = 0; dt < 4; dt++) {
            short8 bv = *(const short8*)&ctxt[(dt * 16 + ml) * CTXT_LD + ks * 32 + q * 8];
            oacc[dt] = __builtin_amdgcn_mfma_f32_16x16x32_bf16(a, bv, oacc[dt], 0, 0, 0);
        }
    }
#pragma unroll
    for (int dt = 0; dt < 4; dt++)
#pragma unroll
        for (int r = 0; r < 4; r++)
            Ob[(size_t)(b * SEQ + nl + q * 4 + r) * DIMX + h * DHE + dt * 16 + ml] =
                f2bf(oacc[dt][r] * dinv[r]);
}

extern "C" void kernel_launch(void* const* d_in, const int* in_sizes, int n_in,
                              void* d_out, int out_size, void* d_ws, size_t ws_size,
                              hipStream_t stream) {
    (void)in_sizes; (void)n_in; (void)out_size; (void)ws_size;
    const float* src  = (const float*)d_in[0];
    const float* proj = (const float*)d_in[1];
    const float* ln1g = (const float*)d_in[2];
    const float* ln1b = (const float*)d_in[3];
    const float* Wq   = (const float*)d_in[4];
    const float* Wk   = (const float*)d_in[5];
    const float* Wv   = (const float*)d_in[6];
    const float* Wo   = (const float*)d_in[7];
    const float* bo   = (const float*)d_in[8];
    const float* ln2g = (const float*)d_in[9];
    const float* ln2b = (const float*)d_in[10];
    const float* W1   = (const float*)d_in[11];
    const float* b1   = (const float*)d_in[12];
    const float* W2   = (const float*)d_in[13];
    const float* b2   = (const float*)d_in[14];
    const float* fcw  = (const float*)d_in[15];
    const float* fcb  = (const float*)d_in[16];
    float* out = (float*)d_out;

    // ---- workspace layout (~155 MiB of 162 safe) ----
    const size_t TD   = (size_t)NTOK * DIMX;
    const size_t PD   = (size_t)PSEQ * DIMX;
    float*    X    = (float*)d_ws;                      // 64 MiB residual fp32
    ushort_t* Hs   = (ushort_t*)(X + TD);               // 16 MiB LN out bf16 (pair)
    ushort_t* KQbf = Hs + PD;                           // 16 MiB K bf16, then Q bf16
    ushort_t* Vt   = KQbf + PD;                         // 16 MiB V^T per-head bf16
    float*    CTXP = (float*)(Vt + PD);                 // 36 MiB ctx partials (32 strips)
    ushort_t* Obuf = (ushort_t*)CTXP;                   // 16 MiB attn-out bf16, aliases CTXP
    ushort_t* CTXbf = (ushort_t*)(CTXP + (size_t)16 * NSTRIP * MP * DHE);  // 592 KiB bf16 CTX^T
    float*    KSUM = (float*)(CTXbf + (size_t)16 * DHE * CTXT_LD);  // 16x288
    unsigned int* KMAX = (unsigned int*)(KSUM + 16 * MP);
    float*    SS   = (float*)(KMAX + 4);                // [8][PSEQ]
    ushort_t* Pbf  = (ushort_t*)(SS + (size_t)NHEADS * PSEQ);  // [288][64] bf16
    ushort_t* Wtb  = Pbf + MP * DHE;                    // 6 MiB weights bf16
    ushort_t* Wqt = Wtb;
    ushort_t* Wkt = Wqt + DIMX * DIMX;
    ushort_t* Wvt = Wkt + DIMX * DIMX;
    ushort_t* Wot = Wvt + DIMX * DIMX;
    ushort_t* W1t = Wot + DIMX * DIMX;         // [FFD, DIMX]
    ushort_t* W2t = W1t + (size_t)DIMX * FFD;  // [DIMX, FFD]
    ushort_t* Hid = KQbf;  // FF hidden 64 MiB: aliases KQbf+Vt+CTXP head (all dead in FF)

    hipMemcpyAsync(X, src, sizeof(float) * TD, hipMemcpyDeviceToDevice, stream);

    dim3 gP(PSEQ / 128, DIMX / 128);   // (128,4)  nwg=512 (div 8 for XCD swizzle)
    dim3 gF1(PSEQ / 128, FFD / 128);   // (128,16) nwg=2048
    const int lnGrid = PSEQ / 4;       // 4096
    for (int L = 0; L < NLAYER; L++) {
        const float* pj = proj + (size_t)L * NB * DHE;
        wconv4_kernel<<<dim3(16, 16, 4), 256, 0, stream>>>(
            Wq + (size_t)L * DIMX * DIMX, Wk + (size_t)L * DIMX * DIMX,
            Wv + (size_t)L * DIMX * DIMX, Wo + (size_t)L * DIMX * DIMX, Wqt);
        wconv_kernel<<<dim3(64, 16), 256, 0, stream>>>(W1 + (size_t)L * DIMX * FFD, W1t, DIMX, FFD);
        wconv_kernel<<<dim3(16, 64), 256, 0, stream>>>(W2 + (size_t)L * FFD * DIMX, W2t, FFD, DIMX);
        projconv_kernel<<<(MP * DHE + 255) / 256, 256, 0, stream>>>(pj, Pbf);
        zero_kernel<<<1, 256, 0, stream>>>((float*)KMAX, 1);
        // --- phase A: global key-feature max over both pairs ---
        for (int p = 0; p < 2; p++) {
            const float* Xp = X + (size_t)p * PD;
            ln_bf16_kernel<<<lnGrid, 256, 0, stream>>>(Xp, ln1g + L * DIMX, ln1b + L * DIMX, Hs);
            gemm_mfma<5><<<gP, 256, 0, stream>>>(Hs, Wkt, nullptr, nullptr, KQbf, SS, PSEQ, DIMX, DIMX);
            kmax_kernel<<<512, 512, 0, stream>>>(KQbf, Pbf, KMAX);
        }
        // --- phase B: attention + FF per pair (p=1 first: Hs/KQbf/SS still hold pair-1) ---
        for (int pp = 0; pp < 2; pp++) {
            int p = 1 - pp;
            float* Xp = X + (size_t)p * PD;
            if (p == 0) {
                ln_bf16_kernel<<<lnGrid, 256, 0, stream>>>(Xp, ln1g + L * DIMX, ln1b + L * DIMX, Hs);
                gemm_mfma<5><<<gP, 256, 0, stream>>>(Hs, Wkt, nullptr, nullptr, KQbf, SS, PSEQ, DIMX, DIMX);
            }
            gemm_mfma<4><<<gP, 256, 0, stream>>>(Hs, Wvt, nullptr, nullptr, Vt, nullptr, PSEQ, DIMX, DIMX);
            zero_kernel<<<(16 * MP + 255) / 256, 256, 0, stream>>>(KSUM, 16 * MP);
            kctx_kernel<<<16 * NSTRIP, 512, 0, stream>>>(KQbf, Pbf, SS, KMAX, Vt, CTXP, KSUM);
            ctx_reduce_kernel<<<(16 * MP * DHE + 255) / 256, 256, 0, stream>>>(CTXP, CTXbf);
            gemm_mfma<5><<<gP, 256, 0, stream>>>(Hs, Wqt, nullptr, nullptr, KQbf, SS, PSEQ, DIMX, DIMX);
            qo_kernel<<<2048, 256, 0, stream>>>(KQbf, Pbf, SS, CTXbf, KSUM, Obuf);
            gemm_mfma<1><<<gP, 256, 0, stream>>>(Obuf, Wot, bo + L * DIMX, Xp, nullptr, nullptr, PSEQ, DIMX, DIMX);
            // --- FF ---
            ln_bf16_kernel<<<lnGrid, 256, 0, stream>>>(Xp, ln2g + L * DIMX, ln2b + L * DIMX, Hs);
            gemm_mfma<2><<<gF1, 256, 0, stream>>>(Hs, W1t, b1 + L * FFD, nullptr, Hid, nullptr, PSEQ, FFD, DIMX);
            gemm_mfma<1><<<gP, 256, 0, stream>>>(Hid, W2t, b2 + L * DIMX, Xp, nullptr, nullptr, PSEQ, DIMX, FFD);
        }
    }
    gemm_kernel<0, 0><<<dim3(NTOK / 128, 1), 256, 0, stream>>>(X, fcw, fcb, out, NTOK, OUTD, DIMX);
}